// Round 2
// baseline (6405.973 us; speedup 1.0000x reference)
//
#include <hip/hip_runtime.h>
#include <hip/hip_bf16.h>

typedef __hip_bfloat16 bf16;

#define BATCH 8
#define NPTS 2048
#define KNN 20
#define NK (NPTS*KNN)      // 40960
#define P4 (BATCH*NK)      // 327680
#define EMB 512

__device__ __forceinline__ float toF(float v){ return v; }
__device__ __forceinline__ float toF(bf16 v){ return __bfloat162float(v); }
__device__ __forceinline__ void stv(float* p, float v){ *p = v; }
__device__ __forceinline__ void stv(bf16* p, float v){ *p = __float2bfloat16(v); }

// float atomic max/min via integer punning (works for all signs; init -inf/+inf)
__device__ __forceinline__ void atomicMaxF(float* a, float v){
    if (v >= 0.f) atomicMax((int*)a, __float_as_int(v));
    else          atomicMin((unsigned int*)a, (unsigned int)__float_as_int(v));
}
__device__ __forceinline__ void atomicMinF(float* a, float v){
    if (v >= 0.f) atomicMin((int*)a, __float_as_int(v));
    else          atomicMax((unsigned int*)a, (unsigned int)__float_as_int(v));
}

// ---------------- init: zero sums, set identity-BN params ----------------
__global__ void init_stats(float* sums, float* ident)
{
    int t = blockIdx.x*256 + threadIdx.x;
    if (t < 2048) sums[t] = 0.f;                 // sum[1024] + sumsq[1024]
    if (t < 2048) {
        // ident layout: mean[512]=0, rstd[512]=1, gamma[512]=1, beta[512]=0
        float v = (t < 512) ? 0.f : (t < 1536) ? 1.f : 0.f;
        ident[t] = v;
    }
}

__global__ void pool_init(float* pmax, float* pmin)
{
    int t = blockIdx.x*256 + threadIdx.x;        // 8*256*2048 = 4194304 total
    pmax[t] = -3.0e38f;
    pmin[t] =  3.0e38f;
}

// ---------------- KNN: one thread per (b,n), top-20 by neg squared dist ----------------
__global__ void knn_kernel(const float* __restrict__ x, int* __restrict__ idx)
{
    #pragma clang fp contract(off)
    __shared__ float sx[3*NPTS];
    int b  = blockIdx.x >> 3;     // 8 blocks of 256 threads per batch
    int nb = blockIdx.x & 7;
    const float* xb = x + (size_t)b*3*NPTS;
    for (int i = threadIdx.x; i < 3*NPTS; i += 256) sx[i] = xb[i];
    __syncthreads();
    int n = nb*256 + threadIdx.x;
    float x0 = sx[n], x1 = sx[NPTS+n], x2 = sx[2*NPTS+n];
    float xxn = x0*x0 + x1*x1 + x2*x2;
    float best[KNN]; int bi[KNN];
    #pragma unroll
    for (int i = 0; i < KNN; ++i) { best[i] = -3e38f; bi[i] = 0; }
    float minv = -3e38f;
    for (int m = 0; m < NPTS; ++m) {
        float y0 = sx[m], y1 = sx[NPTS+m], y2 = sx[2*NPTS+m];
        float dot = x0*y0 + x1*y1 + x2*y2;
        float xxm = y0*y0 + y1*y1 + y2*y2;
        float v = -xxn - (-2.f*dot) - xxm;     // matches reference expression order
        if (v > minv) {
            int p = KNN-1;
            while (p > 0 && best[p-1] < v) { best[p] = best[p-1]; bi[p] = bi[p-1]; --p; }
            best[p] = v; bi[p] = m;
            minv = best[KNN-1];
        }
    }
    size_t base = ((size_t)b*NPTS + n)*KNN;
    for (int i = 0; i < KNN; ++i) idx[base+i] = bi[i];
}

// ---------------- conv1: gather edge features + 6->64 pointwise conv ----------------
__global__ void conv1_kernel(const float* __restrict__ x, const int* __restrict__ idx,
                             const float* __restrict__ W1, bf16* __restrict__ h1)
{
    int p = blockIdx.x*256 + threadIdx.x;
    if (p >= P4) return;
    int b = p / NK;
    int r = p - b*NK;       // n*KNN + kk
    int n = r / KNN;
    int j = idx[p];
    const float* xb = x + (size_t)b*3*NPTS;
    float c0 = xb[n],      c1 = xb[NPTS+n],   c2 = xb[2*NPTS+n];
    float d0 = xb[j]-c0,   d1 = xb[NPTS+j]-c1, d2 = xb[2*NPTS+j]-c2;
    bf16* outp = h1 + (size_t)b*64*NK + r;
    #pragma unroll 8
    for (int o = 0; o < 64; ++o) {
        const float* wr = W1 + o*6;
        float acc = wr[0]*d0 + wr[1]*d1 + wr[2]*d2 + wr[3]*c0 + wr[4]*c1 + wr[5]*c2;
        outp[(size_t)o*NK] = __float2bfloat16(acc);
    }
}

// ---------------- per-channel sum / sumsq (grid = (C, BATCH)) ----------------
template<typename T>
__global__ void stats_kernel(const T* __restrict__ h, float* __restrict__ sum,
                             float* __restrict__ sumsq, int C, int R)
{
    int c = blockIdx.x, b = blockIdx.y;
    const T* hp = h + ((size_t)b*C + c)*R;
    float s = 0.f, ss = 0.f;
    for (int r = threadIdx.x; r < R; r += 256) {
        float v = toF(hp[r]);
        s += v; ss += v*v;
    }
    #pragma unroll
    for (int off = 32; off > 0; off >>= 1) {
        s  += __shfl_down(s, off);
        ss += __shfl_down(ss, off);
    }
    __shared__ float as_[4], bs_[4];
    int w = threadIdx.x >> 6;
    if ((threadIdx.x & 63) == 0) { as_[w] = s; bs_[w] = ss; }
    __syncthreads();
    if (threadIdx.x == 0) {
        atomicAdd(&sum[c],   as_[0]+as_[1]+as_[2]+as_[3]);
        atomicAdd(&sumsq[c], bs_[0]+bs_[1]+bs_[2]+bs_[3]);
    }
}

__global__ void finalize_stats(const float* __restrict__ sum, const float* __restrict__ sumsq,
                               float* __restrict__ mean, float* __restrict__ rstd,
                               int C, float invCnt)
{
    int c = blockIdx.x*256 + threadIdx.x;
    if (c < C) {
        float m = sum[c]*invCnt;
        float var = sumsq[c]*invCnt - m*m;
        mean[c] = m;
        rstd[c] = rsqrtf(var + 1e-5f);
    }
}

// ---------------- tiled GEMM with BN+ReLU applied to the INPUT on load ----------------
// out[b, row, r] = sum_c W[row,c] * relu(bn(in[b,c,r]))
template<typename InT, typename OutT>
__global__ __launch_bounds__(256)
void gemm_act(const float* __restrict__ W, const InT* __restrict__ in,
              OutT* __restrict__ out,
              const float* __restrict__ mean, const float* __restrict__ rstd,
              const float* __restrict__ gamma, const float* __restrict__ beta,
              int Cout, int Cin, int R)
{
    __shared__ float As[16][64];
    __shared__ float Wsm[16][64];
    const int tid = threadIdx.x;
    const int tx = tid & 15, ty = tid >> 4;
    const int colBase = blockIdx.x * 64;
    const int rowBase = blockIdx.y * 64;
    const int b = colBase / R;           // R % 64 == 0 -> tile within one batch
    const int r0 = colBase - b * R;
    const InT* inb = in + (size_t)b * Cin * R;

    float acc[4][4] = {};
    for (int k0 = 0; k0 < Cin; k0 += 16) {
        #pragma unroll
        for (int l = 0; l < 4; ++l) {
            int li = tid + l*256;
            int kk = li >> 6, col = li & 63;
            int c = k0 + kk;
            float v = toF(inb[(size_t)c*R + r0 + col]);
            As[kk][col] = fmaxf(fmaf((v - mean[c]) * rstd[c], gamma[c], beta[c]), 0.f);
        }
        #pragma unroll
        for (int l = 0; l < 4; ++l) {
            int li = tid + l*256;
            int kk = li & 15, row = li >> 4;
            Wsm[kk][row] = W[(size_t)(rowBase + row)*Cin + k0 + kk];
        }
        __syncthreads();
        #pragma unroll
        for (int kk = 0; kk < 16; ++kk) {
            float a0 = As[kk][tx*4+0], a1 = As[kk][tx*4+1], a2 = As[kk][tx*4+2], a3 = As[kk][tx*4+3];
            float w0 = Wsm[kk][ty*4+0], w1 = Wsm[kk][ty*4+1], w2 = Wsm[kk][ty*4+2], w3 = Wsm[kk][ty*4+3];
            acc[0][0] = fmaf(w0,a0,acc[0][0]); acc[0][1] = fmaf(w0,a1,acc[0][1]);
            acc[0][2] = fmaf(w0,a2,acc[0][2]); acc[0][3] = fmaf(w0,a3,acc[0][3]);
            acc[1][0] = fmaf(w1,a0,acc[1][0]); acc[1][1] = fmaf(w1,a1,acc[1][1]);
            acc[1][2] = fmaf(w1,a2,acc[1][2]); acc[1][3] = fmaf(w1,a3,acc[1][3]);
            acc[2][0] = fmaf(w2,a0,acc[2][0]); acc[2][1] = fmaf(w2,a1,acc[2][1]);
            acc[2][2] = fmaf(w2,a2,acc[2][2]); acc[2][3] = fmaf(w2,a3,acc[2][3]);
            acc[3][0] = fmaf(w3,a0,acc[3][0]); acc[3][1] = fmaf(w3,a1,acc[3][1]);
            acc[3][2] = fmaf(w3,a2,acc[3][2]); acc[3][3] = fmaf(w3,a3,acc[3][3]);
        }
        __syncthreads();
    }
    #pragma unroll
    for (int i = 0; i < 4; ++i) {
        size_t obase = ((size_t)b*Cout + rowBase + ty*4 + i)*R + r0 + tx*4;
        stv(&out[obase+0], acc[i][0]);
        stv(&out[obase+1], acc[i][1]);
        stv(&out[obase+2], acc[i][2]);
        stv(&out[obase+3], acc[i][3]);
    }
}

// ---------------- layer-4 GEMM, fused: no h4 materialization ----------------
// Computes conv4 tiles, atomically accumulates per-channel sum/sumsq, and
// atomically max/min-pools raw values over k into pmax/pmin (B,256,NPTS).
__global__ __launch_bounds__(256)
void gemm4_fused(const float* __restrict__ W, const bf16* __restrict__ in,
                 const float* __restrict__ mean, const float* __restrict__ rstd,
                 const float* __restrict__ gamma, const float* __restrict__ beta,
                 float* __restrict__ pmax, float* __restrict__ pmin,
                 float* __restrict__ sum, float* __restrict__ sumsq)
{
    const int Cin = 128, R = NK;
    __shared__ float As[16][64];
    __shared__ float Wsm[16][64];
    const int tid = threadIdx.x;
    const int tx = tid & 15, ty = tid >> 4;
    const int colBase = blockIdx.x * 64;
    const int rowBase = blockIdx.y * 64;
    const int b = colBase / R;
    const int r0 = colBase - b * R;
    const bf16* inb = in + (size_t)b * Cin * R;

    float acc[4][4] = {};
    for (int k0 = 0; k0 < Cin; k0 += 16) {
        #pragma unroll
        for (int l = 0; l < 4; ++l) {
            int li = tid + l*256;
            int kk = li >> 6, col = li & 63;
            int c = k0 + kk;
            float v = __bfloat162float(inb[(size_t)c*R + r0 + col]);
            As[kk][col] = fmaxf(fmaf((v - mean[c]) * rstd[c], gamma[c], beta[c]), 0.f);
        }
        #pragma unroll
        for (int l = 0; l < 4; ++l) {
            int li = tid + l*256;
            int kk = li & 15, row = li >> 4;
            Wsm[kk][row] = W[(size_t)(rowBase + row)*Cin + k0 + kk];
        }
        __syncthreads();
        #pragma unroll
        for (int kk = 0; kk < 16; ++kk) {
            float a0 = As[kk][tx*4+0], a1 = As[kk][tx*4+1], a2 = As[kk][tx*4+2], a3 = As[kk][tx*4+3];
            float w0 = Wsm[kk][ty*4+0], w1 = Wsm[kk][ty*4+1], w2 = Wsm[kk][ty*4+2], w3 = Wsm[kk][ty*4+3];
            acc[0][0] = fmaf(w0,a0,acc[0][0]); acc[0][1] = fmaf(w0,a1,acc[0][1]);
            acc[0][2] = fmaf(w0,a2,acc[0][2]); acc[0][3] = fmaf(w0,a3,acc[0][3]);
            acc[1][0] = fmaf(w1,a0,acc[1][0]); acc[1][1] = fmaf(w1,a1,acc[1][1]);
            acc[1][2] = fmaf(w1,a2,acc[1][2]); acc[1][3] = fmaf(w1,a3,acc[1][3]);
            acc[2][0] = fmaf(w2,a0,acc[2][0]); acc[2][1] = fmaf(w2,a1,acc[2][1]);
            acc[2][2] = fmaf(w2,a2,acc[2][2]); acc[2][3] = fmaf(w2,a3,acc[2][3]);
            acc[3][0] = fmaf(w3,a0,acc[3][0]); acc[3][1] = fmaf(w3,a1,acc[3][1]);
            acc[3][2] = fmaf(w3,a2,acc[3][2]); acc[3][3] = fmaf(w3,a3,acc[3][3]);
        }
        __syncthreads();
    }

    // ---- fused stats: reduce each row's 4 values across the 16 tx lanes ----
    #pragma unroll
    for (int i = 0; i < 4; ++i) {
        float s  = acc[i][0]+acc[i][1]+acc[i][2]+acc[i][3];
        float q  = acc[i][0]*acc[i][0]+acc[i][1]*acc[i][1]+acc[i][2]*acc[i][2]+acc[i][3]*acc[i][3];
        #pragma unroll
        for (int off = 1; off < 16; off <<= 1) {
            s += __shfl_xor(s, off);
            q += __shfl_xor(q, off);
        }
        if (tx == 0) {
            int c = rowBase + ty*4 + i;
            atomicAdd(&sum[c], s);
            atomicAdd(&sumsq[c], q);
        }
    }

    // ---- fused raw max/min pooling over k (group = KNN consecutive cols) ----
    {
        int rr = r0 + tx*4;        // position within batch, 4 consecutive
        #pragma unroll
        for (int i = 0; i < 4; ++i) {
            int c = rowBase + ty*4 + i;
            float* pmaxc = pmax + ((size_t)b*256 + c)*NPTS;
            float* pminc = pmin + ((size_t)b*256 + c)*NPTS;
            int n = rr / KNN;
            float mx = acc[i][0], mn = acc[i][0];
            #pragma unroll
            for (int j = 1; j < 4; ++j) {
                int nj = (rr + j) / KNN;
                if (nj != n) {
                    atomicMaxF(&pmaxc[n], mx); atomicMinF(&pminc[n], mn);
                    n = nj; mx = acc[i][j]; mn = acc[i][j];
                } else {
                    mx = fmaxf(mx, acc[i][j]); mn = fminf(mn, acc[i][j]);
                }
            }
            atomicMaxF(&pmaxc[n], mx); atomicMinF(&pminc[n], mn);
        }
    }
}

// ---------------- layer-4 pooled values -> BN+ReLU -> cat[256:512] ----------------
__global__ void cat4_kernel(const float* __restrict__ pmax, const float* __restrict__ pmin,
                            const float* __restrict__ mean, const float* __restrict__ rstd,
                            const float* __restrict__ g, const float* __restrict__ be,
                            float* __restrict__ cat)
{
    int t = blockIdx.x*256 + threadIdx.x;   // < 8*256*2048
    int n = t & (NPTS-1);
    int c = (t >> 11) & 255;
    int b = t >> 19;
    float gg = g[c];
    float v = (gg >= 0.f) ? pmax[t] : pmin[t];
    cat[((size_t)b*512 + 256 + c)*NPTS + n] =
        fmaxf(fmaf((v - mean[c])*rstd[c], gg, be[c]), 0.f);
}

// ---------------- k-maxpool of bn+relu'd h into cat (layers 1-3) ----------------
__global__ void maxpool_kernel(const bf16* __restrict__ h,
                               const float* __restrict__ mean, const float* __restrict__ rstd,
                               const float* __restrict__ g, const float* __restrict__ be,
                               float* __restrict__ cat, int C, int coff)
{
    int t = blockIdx.x*256 + threadIdx.x;
    if (t >= BATCH*C*NPTS) return;
    int n = t & (NPTS-1);
    int tmp = t >> 11;
    int c = tmp % C;
    int b = tmp / C;
    const bf16* src = h + ((size_t)(b*C + c)*NPTS + n)*KNN;
    float m = mean[c], rs = rstd[c], gg = g[c], bb = be[c];
    float best = -3e38f;
    #pragma unroll
    for (int kk = 0; kk < KNN; ++kk) {
        float v = __bfloat162float(src[kk]);
        best = fmaxf(best, fmaf((v - m)*rs, gg, bb));
    }
    cat[((size_t)b*512 + coff + c)*NPTS + n] = fmaxf(best, 0.f);
}

// ---------------- final BN+ReLU in place on d_out ----------------
__global__ void final_bn(float* __restrict__ out,
                         const float* __restrict__ mean, const float* __restrict__ rstd,
                         const float* __restrict__ g, const float* __restrict__ be)
{
    int t = blockIdx.x*256 + threadIdx.x;
    if (t >= BATCH*EMB*NPTS) return;
    int c = (t >> 11) & 511;
    float v = out[t];
    out[t] = fmaxf(fmaf((v - mean[c])*rstd[c], g[c], be[c]), 0.f);
}

extern "C" void kernel_launch(void* const* d_in, const int* in_sizes, int n_in,
                              void* d_out, int out_size, void* d_ws, size_t ws_size,
                              hipStream_t stream)
{
    const float* x  = (const float*)d_in[0];
    const float* W1 = (const float*)d_in[2];
    const float* W2 = (const float*)d_in[3];
    const float* W3 = (const float*)d_in[4];
    const float* W4 = (const float*)d_in[5];
    const float* W5 = (const float*)d_in[6];
    const float* g1 = (const float*)d_in[7];  const float* b1 = (const float*)d_in[8];
    const float* g2 = (const float*)d_in[9];  const float* b2 = (const float*)d_in[10];
    const float* g3 = (const float*)d_in[11]; const float* b3 = (const float*)d_in[12];
    const float* g4 = (const float*)d_in[13]; const float* b4 = (const float*)d_in[14];
    const float* g5 = (const float*)d_in[15]; const float* b5 = (const float*)d_in[16];
    float* out = (float*)d_out;

    // workspace layout (~193 MiB):
    //   idx 1.31MB | stats 24KB | region1 42MB (h1, later pmax/pmin 2x16.8MB)
    //   | h2 42MB | h3 84MB | cat 33.5MB
    char* w = (char*)d_ws;
    int*   idx    = (int*)w;
    float* st_    = (float*)(w + 1310720);
    float* sum_   = st_;
    float* sumsq_ = st_ + 1024;
    float* mean_  = st_ + 2048;
    float* rstd_  = st_ + 3072;
    float* ident  = st_ + 4096;   // mean/rstd/gamma/beta x 512
    bf16*  h1     = (bf16*)(w + 1335296);
    float* pmax   = (float*)h1;                       // aliases h1 after it's dead
    float* pmin   = pmax + (size_t)BATCH*256*NPTS;    // +16.78MB
    bf16*  h2     = (bf16*)(w + 1335296 + 41943040);
    bf16*  h3     = (bf16*)(w + 1335296 + 41943040 + 41943040);
    float* cat    = (float*)(w + 1335296 + 41943040 + 41943040 + 83886080);

    init_stats<<<8, 256, 0, stream>>>(sum_, ident);
    knn_kernel<<<64, 256, 0, stream>>>(x, idx);
    conv1_kernel<<<P4/256, 256, 0, stream>>>(x, idx, W1, h1);

    // layer 1 stats + maxpool
    stats_kernel<bf16><<<dim3(64, BATCH), 256, 0, stream>>>(h1, sum_, sumsq_, 64, NK);
    finalize_stats<<<1, 256, 0, stream>>>(sum_, sumsq_, mean_, rstd_, 64, 1.f/P4);
    maxpool_kernel<<<BATCH*64*NPTS/256, 256, 0, stream>>>(h1, mean_, rstd_, g1, b1, cat, 64, 0);

    // layer 2 (reads h1 -> h1 is dead afterwards)
    gemm_act<bf16,bf16><<<dim3(P4/64,1), 256, 0, stream>>>(W2, h1, h2, mean_, rstd_, g1, b1, 64, 64, NK);
    pool_init<<<BATCH*256*NPTS/256, 256, 0, stream>>>(pmax, pmin);   // aliases h1, AFTER gemm2
    stats_kernel<bf16><<<dim3(64, BATCH), 256, 0, stream>>>(h2, sum_+64, sumsq_+64, 64, NK);
    finalize_stats<<<1, 256, 0, stream>>>(sum_+64, sumsq_+64, mean_+64, rstd_+64, 64, 1.f/P4);
    maxpool_kernel<<<BATCH*64*NPTS/256, 256, 0, stream>>>(h2, mean_+64, rstd_+64, g2, b2, cat, 64, 64);

    // layer 3
    gemm_act<bf16,bf16><<<dim3(P4/64,2), 256, 0, stream>>>(W3, h2, h3, mean_+64, rstd_+64, g2, b2, 128, 64, NK);
    stats_kernel<bf16><<<dim3(128, BATCH), 256, 0, stream>>>(h3, sum_+128, sumsq_+128, 128, NK);
    finalize_stats<<<1, 256, 0, stream>>>(sum_+128, sumsq_+128, mean_+128, rstd_+128, 128, 1.f/P4);
    maxpool_kernel<<<BATCH*128*NPTS/256, 256, 0, stream>>>(h3, mean_+128, rstd_+128, g3, b3, cat, 128, 128);

    // layer 4: fused GEMM + stats + raw max/min pooling (no h4 tensor)
    gemm4_fused<<<dim3(P4/64,4), 256, 0, stream>>>(W4, h3, mean_+128, rstd_+128, g3, b3,
                                                   pmax, pmin, sum_+256, sumsq_+256);
    finalize_stats<<<1, 256, 0, stream>>>(sum_+256, sumsq_+256, mean_+256, rstd_+256, 256, 1.f/P4);
    cat4_kernel<<<BATCH*256*NPTS/256, 256, 0, stream>>>(pmax, pmin, mean_+256, rstd_+256, g4, b4, cat);

    // layer 5: 512x512 over B*N columns; cat is already post-activation -> identity BN on load
    gemm_act<float,float><<<dim3(BATCH*NPTS/64,8), 256, 0, stream>>>(W5, cat, out,
        ident, ident+512, ident+1024, ident+1536, 512, 512, NPTS);
    stats_kernel<float><<<dim3(512, BATCH), 256, 0, stream>>>(out, sum_+512, sumsq_+512, 512, NPTS);
    finalize_stats<<<2, 256, 0, stream>>>(sum_+512, sumsq_+512, mean_+512, rstd_+512, 512, 1.f/(BATCH*NPTS));
    final_bn<<<BATCH*EMB*NPTS/256, 256, 0, stream>>>(out, mean_+512, rstd_+512, g5, b5);
}

// Round 3
// 3354.592 us; speedup vs baseline: 1.9096x; 1.9096x over previous
//
#include <hip/hip_runtime.h>
#include <hip/hip_bf16.h>

typedef __hip_bfloat16 bf16;

#define BATCH 8
#define NPTS 2048
#define KNN 20
#define NK (NPTS*KNN)      // 40960
#define P4 (BATCH*NK)      // 327680
#define EMB 512

__device__ __forceinline__ float toF(float v){ return v; }
__device__ __forceinline__ float toF(bf16 v){ return __bfloat162float(v); }
__device__ __forceinline__ void stv(float* p, float v){ *p = v; }
__device__ __forceinline__ void stv(bf16* p, float v){ *p = __float2bfloat16(v); }

// float atomic max/min via integer punning (works for all signs; init -inf/+inf)
__device__ __forceinline__ void atomicMaxF(float* a, float v){
    if (v >= 0.f) atomicMax((int*)a, __float_as_int(v));
    else          atomicMin((unsigned int*)a, (unsigned int)__float_as_int(v));
}
__device__ __forceinline__ void atomicMinF(float* a, float v){
    if (v >= 0.f) atomicMin((int*)a, __float_as_int(v));
    else          atomicMax((unsigned int*)a, (unsigned int)__float_as_int(v));
}

// ---------------- init: zero sums, set identity-BN params ----------------
__global__ void init_stats(float* sums, float* ident)
{
    int t = blockIdx.x*256 + threadIdx.x;
    if (t < 2048) sums[t] = 0.f;                 // sum[1024] + sumsq[1024]
    if (t < 2048) {
        // ident layout: mean[512]=0, rstd[512]=1, gamma[512]=1, beta[512]=0
        float v = (t < 512) ? 0.f : (t < 1536) ? 1.f : 0.f;
        ident[t] = v;
    }
}

__global__ void pool_init(float* pmax, float* pmin)
{
    int t = blockIdx.x*256 + threadIdx.x;        // 8*256*2048 = 4194304 total
    pmax[t] = -3.0e38f;
    pmin[t] =  3.0e38f;
}

// ---------------- KNN: one WAVE per point, register top-20, wave merge ----------------
// Each lane scans 32 candidates (m = lane + 64j, ascending) keeping a top-20
// list via a static branchless compare-swap chain (stays in VGPRs). Then a
// 20-round wave argmax selection merges the 64 lists; ties (equal value) pick
// the smaller index, matching lax.top_k's stable ordering for the chosen SET.
__global__ __launch_bounds__(256)
void knn_kernel(const float* __restrict__ x, int* __restrict__ idx)
{
    #pragma clang fp contract(off)
    __shared__ float sx[3*NPTS];
    const int b  = blockIdx.x / (NPTS/4);     // 512 blocks per batch
    const int nb = blockIdx.x % (NPTS/4);     // group of 4 points per block
    const float* xb = x + (size_t)b*3*NPTS;
    for (int i = threadIdx.x; i < 3*NPTS; i += 256) sx[i] = xb[i];
    __syncthreads();

    const int wave = threadIdx.x >> 6;
    const int lane = threadIdx.x & 63;
    const int n = nb*4 + wave;

    const float x0 = sx[n], x1 = sx[NPTS+n], x2 = sx[2*NPTS+n];
    const float xxn = x0*x0 + x1*x1 + x2*x2;

    float best[KNN]; int bi[KNN];
    #pragma unroll
    for (int i = 0; i < KNN; ++i) { best[i] = -3e38f; bi[i] = 0x7fffffff; }

    #pragma unroll
    for (int j = 0; j < NPTS/64; ++j) {
        int m = lane + j*64;
        float y0 = sx[m], y1 = sx[NPTS+m], y2 = sx[2*NPTS+m];
        float dot = x0*y0 + x1*y1 + x2*y2;
        float xxm = y0*y0 + y1*y1 + y2*y2;
        float v = -xxn - (-2.f*dot) - xxm;    // same rounding as reference path
        int mi = m;
        #pragma unroll
        for (int i = 0; i < KNN; ++i) {       // branchless sorted insert
            bool sw = v > best[i];
            float tv = sw ? best[i] : v;
            int   ti = sw ? bi[i]   : mi;
            best[i] = sw ? v  : best[i];
            bi[i]   = sw ? mi : bi[i];
            v = tv; mi = ti;
        }
    }

    // wave-wide merge: 20 rounds, pop global (max value, min index)
    size_t obase = ((size_t)b*NPTS + n)*KNN;
    #pragma unroll 1
    for (int s = 0; s < KNN; ++s) {
        float mv = best[0]; int mi = bi[0];
        #pragma unroll
        for (int off = 1; off < 64; off <<= 1) {
            float ov = __shfl_xor(mv, off);
            int   oi = __shfl_xor(mi, off);
            if (ov > mv || (ov == mv && oi < mi)) { mv = ov; mi = oi; }
        }
        bool win = (best[0] == mv) && (bi[0] == mi);
        #pragma unroll
        for (int i = 0; i < KNN-1; ++i) {     // winner shifts its list up
            best[i] = win ? best[i+1] : best[i];
            bi[i]   = win ? bi[i+1]   : bi[i];
        }
        best[KNN-1] = win ? -3e38f      : best[KNN-1];
        bi[KNN-1]   = win ? 0x7fffffff  : bi[KNN-1];
        if (lane == 0) idx[obase + s] = mi;
    }
}

// ---------------- conv1: gather edge features + 6->64 pointwise conv ----------------
__global__ void conv1_kernel(const float* __restrict__ x, const int* __restrict__ idx,
                             const float* __restrict__ W1, bf16* __restrict__ h1)
{
    int p = blockIdx.x*256 + threadIdx.x;
    if (p >= P4) return;
    int b = p / NK;
    int r = p - b*NK;       // n*KNN + kk
    int n = r / KNN;
    int j = idx[p];
    const float* xb = x + (size_t)b*3*NPTS;
    float c0 = xb[n],      c1 = xb[NPTS+n],   c2 = xb[2*NPTS+n];
    float d0 = xb[j]-c0,   d1 = xb[NPTS+j]-c1, d2 = xb[2*NPTS+j]-c2;
    bf16* outp = h1 + (size_t)b*64*NK + r;
    #pragma unroll 8
    for (int o = 0; o < 64; ++o) {
        const float* wr = W1 + o*6;
        float acc = wr[0]*d0 + wr[1]*d1 + wr[2]*d2 + wr[3]*c0 + wr[4]*c1 + wr[5]*c2;
        outp[(size_t)o*NK] = __float2bfloat16(acc);
    }
}

// ---------------- per-channel sum / sumsq (grid = (C, BATCH)) ----------------
template<typename T>
__global__ void stats_kernel(const T* __restrict__ h, float* __restrict__ sum,
                             float* __restrict__ sumsq, int C, int R)
{
    int c = blockIdx.x, b = blockIdx.y;
    const T* hp = h + ((size_t)b*C + c)*R;
    float s = 0.f, ss = 0.f;
    for (int r = threadIdx.x; r < R; r += 256) {
        float v = toF(hp[r]);
        s += v; ss += v*v;
    }
    #pragma unroll
    for (int off = 32; off > 0; off >>= 1) {
        s  += __shfl_down(s, off);
        ss += __shfl_down(ss, off);
    }
    __shared__ float as_[4], bs_[4];
    int w = threadIdx.x >> 6;
    if ((threadIdx.x & 63) == 0) { as_[w] = s; bs_[w] = ss; }
    __syncthreads();
    if (threadIdx.x == 0) {
        atomicAdd(&sum[c],   as_[0]+as_[1]+as_[2]+as_[3]);
        atomicAdd(&sumsq[c], bs_[0]+bs_[1]+bs_[2]+bs_[3]);
    }
}

__global__ void finalize_stats(const float* __restrict__ sum, const float* __restrict__ sumsq,
                               float* __restrict__ mean, float* __restrict__ rstd,
                               int C, float invCnt)
{
    int c = blockIdx.x*256 + threadIdx.x;
    if (c < C) {
        float m = sum[c]*invCnt;
        float var = sumsq[c]*invCnt - m*m;
        mean[c] = m;
        rstd[c] = rsqrtf(var + 1e-5f);
    }
}

// ---------------- tiled GEMM with BN+ReLU applied to the INPUT on load ----------------
// out[b, row, r] = sum_c W[row,c] * relu(bn(in[b,c,r]))
template<typename InT, typename OutT>
__global__ __launch_bounds__(256)
void gemm_act(const float* __restrict__ W, const InT* __restrict__ in,
              OutT* __restrict__ out,
              const float* __restrict__ mean, const float* __restrict__ rstd,
              const float* __restrict__ gamma, const float* __restrict__ beta,
              int Cout, int Cin, int R)
{
    __shared__ float As[16][64];
    __shared__ float Wsm[16][64];
    const int tid = threadIdx.x;
    const int tx = tid & 15, ty = tid >> 4;
    const int colBase = blockIdx.x * 64;
    const int rowBase = blockIdx.y * 64;
    const int b = colBase / R;           // R % 64 == 0 -> tile within one batch
    const int r0 = colBase - b * R;
    const InT* inb = in + (size_t)b * Cin * R;

    float acc[4][4] = {};
    for (int k0 = 0; k0 < Cin; k0 += 16) {
        #pragma unroll
        for (int l = 0; l < 4; ++l) {
            int li = tid + l*256;
            int kk = li >> 6, col = li & 63;
            int c = k0 + kk;
            float v = toF(inb[(size_t)c*R + r0 + col]);
            As[kk][col] = fmaxf(fmaf((v - mean[c]) * rstd[c], gamma[c], beta[c]), 0.f);
        }
        #pragma unroll
        for (int l = 0; l < 4; ++l) {
            int li = tid + l*256;
            int kk = li & 15, row = li >> 4;
            Wsm[kk][row] = W[(size_t)(rowBase + row)*Cin + k0 + kk];
        }
        __syncthreads();
        #pragma unroll
        for (int kk = 0; kk < 16; ++kk) {
            float a0 = As[kk][tx*4+0], a1 = As[kk][tx*4+1], a2 = As[kk][tx*4+2], a3 = As[kk][tx*4+3];
            float w0 = Wsm[kk][ty*4+0], w1 = Wsm[kk][ty*4+1], w2 = Wsm[kk][ty*4+2], w3 = Wsm[kk][ty*4+3];
            acc[0][0] = fmaf(w0,a0,acc[0][0]); acc[0][1] = fmaf(w0,a1,acc[0][1]);
            acc[0][2] = fmaf(w0,a2,acc[0][2]); acc[0][3] = fmaf(w0,a3,acc[0][3]);
            acc[1][0] = fmaf(w1,a0,acc[1][0]); acc[1][1] = fmaf(w1,a1,acc[1][1]);
            acc[1][2] = fmaf(w1,a2,acc[1][2]); acc[1][3] = fmaf(w1,a3,acc[1][3]);
            acc[2][0] = fmaf(w2,a0,acc[2][0]); acc[2][1] = fmaf(w2,a1,acc[2][1]);
            acc[2][2] = fmaf(w2,a2,acc[2][2]); acc[2][3] = fmaf(w2,a3,acc[2][3]);
            acc[3][0] = fmaf(w3,a0,acc[3][0]); acc[3][1] = fmaf(w3,a1,acc[3][1]);
            acc[3][2] = fmaf(w3,a2,acc[3][2]); acc[3][3] = fmaf(w3,a3,acc[3][3]);
        }
        __syncthreads();
    }
    #pragma unroll
    for (int i = 0; i < 4; ++i) {
        size_t obase = ((size_t)b*Cout + rowBase + ty*4 + i)*R + r0 + tx*4;
        stv(&out[obase+0], acc[i][0]);
        stv(&out[obase+1], acc[i][1]);
        stv(&out[obase+2], acc[i][2]);
        stv(&out[obase+3], acc[i][3]);
    }
}

// ---------------- layer-4 GEMM, fused: no h4 materialization ----------------
__global__ __launch_bounds__(256)
void gemm4_fused(const float* __restrict__ W, const bf16* __restrict__ in,
                 const float* __restrict__ mean, const float* __restrict__ rstd,
                 const float* __restrict__ gamma, const float* __restrict__ beta,
                 float* __restrict__ pmax, float* __restrict__ pmin,
                 float* __restrict__ sum, float* __restrict__ sumsq)
{
    const int Cin = 128, R = NK;
    __shared__ float As[16][64];
    __shared__ float Wsm[16][64];
    const int tid = threadIdx.x;
    const int tx = tid & 15, ty = tid >> 4;
    const int colBase = blockIdx.x * 64;
    const int rowBase = blockIdx.y * 64;
    const int b = colBase / R;
    const int r0 = colBase - b * R;
    const bf16* inb = in + (size_t)b * Cin * R;

    float acc[4][4] = {};
    for (int k0 = 0; k0 < Cin; k0 += 16) {
        #pragma unroll
        for (int l = 0; l < 4; ++l) {
            int li = tid + l*256;
            int kk = li >> 6, col = li & 63;
            int c = k0 + kk;
            float v = __bfloat162float(inb[(size_t)c*R + r0 + col]);
            As[kk][col] = fmaxf(fmaf((v - mean[c]) * rstd[c], gamma[c], beta[c]), 0.f);
        }
        #pragma unroll
        for (int l = 0; l < 4; ++l) {
            int li = tid + l*256;
            int kk = li & 15, row = li >> 4;
            Wsm[kk][row] = W[(size_t)(rowBase + row)*Cin + k0 + kk];
        }
        __syncthreads();
        #pragma unroll
        for (int kk = 0; kk < 16; ++kk) {
            float a0 = As[kk][tx*4+0], a1 = As[kk][tx*4+1], a2 = As[kk][tx*4+2], a3 = As[kk][tx*4+3];
            float w0 = Wsm[kk][ty*4+0], w1 = Wsm[kk][ty*4+1], w2 = Wsm[kk][ty*4+2], w3 = Wsm[kk][ty*4+3];
            acc[0][0] = fmaf(w0,a0,acc[0][0]); acc[0][1] = fmaf(w0,a1,acc[0][1]);
            acc[0][2] = fmaf(w0,a2,acc[0][2]); acc[0][3] = fmaf(w0,a3,acc[0][3]);
            acc[1][0] = fmaf(w1,a0,acc[1][0]); acc[1][1] = fmaf(w1,a1,acc[1][1]);
            acc[1][2] = fmaf(w1,a2,acc[1][2]); acc[1][3] = fmaf(w1,a3,acc[1][3]);
            acc[2][0] = fmaf(w2,a0,acc[2][0]); acc[2][1] = fmaf(w2,a1,acc[2][1]);
            acc[2][2] = fmaf(w2,a2,acc[2][2]); acc[2][3] = fmaf(w2,a3,acc[2][3]);
            acc[3][0] = fmaf(w3,a0,acc[3][0]); acc[3][1] = fmaf(w3,a1,acc[3][1]);
            acc[3][2] = fmaf(w3,a2,acc[3][2]); acc[3][3] = fmaf(w3,a3,acc[3][3]);
        }
        __syncthreads();
    }

    // ---- fused stats: reduce each row's 4 values across the 16 tx lanes ----
    #pragma unroll
    for (int i = 0; i < 4; ++i) {
        float s  = acc[i][0]+acc[i][1]+acc[i][2]+acc[i][3];
        float q  = acc[i][0]*acc[i][0]+acc[i][1]*acc[i][1]+acc[i][2]*acc[i][2]+acc[i][3]*acc[i][3];
        #pragma unroll
        for (int off = 1; off < 16; off <<= 1) {
            s += __shfl_xor(s, off);
            q += __shfl_xor(q, off);
        }
        if (tx == 0) {
            int c = rowBase + ty*4 + i;
            atomicAdd(&sum[c], s);
            atomicAdd(&sumsq[c], q);
        }
    }

    // ---- fused raw max/min pooling over k (group = KNN consecutive cols) ----
    {
        int rr = r0 + tx*4;        // position within batch, 4 consecutive
        #pragma unroll
        for (int i = 0; i < 4; ++i) {
            int c = rowBase + ty*4 + i;
            float* pmaxc = pmax + ((size_t)b*256 + c)*NPTS;
            float* pminc = pmin + ((size_t)b*256 + c)*NPTS;
            int n = rr / KNN;
            float mx = acc[i][0], mn = acc[i][0];
            #pragma unroll
            for (int j = 1; j < 4; ++j) {
                int nj = (rr + j) / KNN;
                if (nj != n) {
                    atomicMaxF(&pmaxc[n], mx); atomicMinF(&pminc[n], mn);
                    n = nj; mx = acc[i][j]; mn = acc[i][j];
                } else {
                    mx = fmaxf(mx, acc[i][j]); mn = fminf(mn, acc[i][j]);
                }
            }
            atomicMaxF(&pmaxc[n], mx); atomicMinF(&pminc[n], mn);
        }
    }
}

// ---------------- layer-4 pooled values -> BN+ReLU -> cat[256:512] ----------------
__global__ void cat4_kernel(const float* __restrict__ pmax, const float* __restrict__ pmin,
                            const float* __restrict__ mean, const float* __restrict__ rstd,
                            const float* __restrict__ g, const float* __restrict__ be,
                            float* __restrict__ cat)
{
    int t = blockIdx.x*256 + threadIdx.x;   // < 8*256*2048
    int n = t & (NPTS-1);
    int c = (t >> 11) & 255;
    int b = t >> 19;
    float gg = g[c];
    float v = (gg >= 0.f) ? pmax[t] : pmin[t];
    cat[((size_t)b*512 + 256 + c)*NPTS + n] =
        fmaxf(fmaf((v - mean[c])*rstd[c], gg, be[c]), 0.f);
}

// ---------------- k-maxpool of bn+relu'd h into cat (layers 1-3) ----------------
__global__ void maxpool_kernel(const bf16* __restrict__ h,
                               const float* __restrict__ mean, const float* __restrict__ rstd,
                               const float* __restrict__ g, const float* __restrict__ be,
                               float* __restrict__ cat, int C, int coff)
{
    int t = blockIdx.x*256 + threadIdx.x;
    if (t >= BATCH*C*NPTS) return;
    int n = t & (NPTS-1);
    int tmp = t >> 11;
    int c = tmp % C;
    int b = tmp / C;
    const bf16* src = h + ((size_t)(b*C + c)*NPTS + n)*KNN;
    float m = mean[c], rs = rstd[c], gg = g[c], bb = be[c];
    float best = -3e38f;
    #pragma unroll
    for (int kk = 0; kk < KNN; ++kk) {
        float v = __bfloat162float(src[kk]);
        best = fmaxf(best, fmaf((v - m)*rs, gg, bb));
    }
    cat[((size_t)b*512 + coff + c)*NPTS + n] = fmaxf(best, 0.f);
}

// ---------------- final BN+ReLU in place on d_out ----------------
__global__ void final_bn(float* __restrict__ out,
                         const float* __restrict__ mean, const float* __restrict__ rstd,
                         const float* __restrict__ g, const float* __restrict__ be)
{
    int t = blockIdx.x*256 + threadIdx.x;
    if (t >= BATCH*EMB*NPTS) return;
    int c = (t >> 11) & 511;
    float v = out[t];
    out[t] = fmaxf(fmaf((v - mean[c])*rstd[c], g[c], be[c]), 0.f);
}

extern "C" void kernel_launch(void* const* d_in, const int* in_sizes, int n_in,
                              void* d_out, int out_size, void* d_ws, size_t ws_size,
                              hipStream_t stream)
{
    const float* x  = (const float*)d_in[0];
    const float* W1 = (const float*)d_in[2];
    const float* W2 = (const float*)d_in[3];
    const float* W3 = (const float*)d_in[4];
    const float* W4 = (const float*)d_in[5];
    const float* W5 = (const float*)d_in[6];
    const float* g1 = (const float*)d_in[7];  const float* b1 = (const float*)d_in[8];
    const float* g2 = (const float*)d_in[9];  const float* b2 = (const float*)d_in[10];
    const float* g3 = (const float*)d_in[11]; const float* b3 = (const float*)d_in[12];
    const float* g4 = (const float*)d_in[13]; const float* b4 = (const float*)d_in[14];
    const float* g5 = (const float*)d_in[15]; const float* b5 = (const float*)d_in[16];
    float* out = (float*)d_out;

    // workspace layout (~193 MiB):
    //   idx 1.31MB | stats 24KB | region1 42MB (h1, later pmax/pmin 2x16.8MB)
    //   | h2 42MB | h3 84MB | cat 33.5MB
    char* w = (char*)d_ws;
    int*   idx    = (int*)w;
    float* st_    = (float*)(w + 1310720);
    float* sum_   = st_;
    float* sumsq_ = st_ + 1024;
    float* mean_  = st_ + 2048;
    float* rstd_  = st_ + 3072;
    float* ident  = st_ + 4096;   // mean/rstd/gamma/beta x 512
    bf16*  h1     = (bf16*)(w + 1335296);
    float* pmax   = (float*)h1;                       // aliases h1 after it's dead
    float* pmin   = pmax + (size_t)BATCH*256*NPTS;    // +16.78MB
    bf16*  h2     = (bf16*)(w + 1335296 + 41943040);
    bf16*  h3     = (bf16*)(w + 1335296 + 41943040 + 41943040);
    float* cat    = (float*)(w + 1335296 + 41943040 + 41943040 + 83886080);

    init_stats<<<8, 256, 0, stream>>>(sum_, ident);
    knn_kernel<<<BATCH*NPTS/4, 256, 0, stream>>>(x, idx);
    conv1_kernel<<<P4/256, 256, 0, stream>>>(x, idx, W1, h1);

    // layer 1 stats + maxpool
    stats_kernel<bf16><<<dim3(64, BATCH), 256, 0, stream>>>(h1, sum_, sumsq_, 64, NK);
    finalize_stats<<<1, 256, 0, stream>>>(sum_, sumsq_, mean_, rstd_, 64, 1.f/P4);
    maxpool_kernel<<<BATCH*64*NPTS/256, 256, 0, stream>>>(h1, mean_, rstd_, g1, b1, cat, 64, 0);

    // layer 2 (reads h1 -> h1 is dead afterwards)
    gemm_act<bf16,bf16><<<dim3(P4/64,1), 256, 0, stream>>>(W2, h1, h2, mean_, rstd_, g1, b1, 64, 64, NK);
    pool_init<<<BATCH*256*NPTS/256, 256, 0, stream>>>(pmax, pmin);   // aliases h1, AFTER gemm2
    stats_kernel<bf16><<<dim3(64, BATCH), 256, 0, stream>>>(h2, sum_+64, sumsq_+64, 64, NK);
    finalize_stats<<<1, 256, 0, stream>>>(sum_+64, sumsq_+64, mean_+64, rstd_+64, 64, 1.f/P4);
    maxpool_kernel<<<BATCH*64*NPTS/256, 256, 0, stream>>>(h2, mean_+64, rstd_+64, g2, b2, cat, 64, 64);

    // layer 3
    gemm_act<bf16,bf16><<<dim3(P4/64,2), 256, 0, stream>>>(W3, h2, h3, mean_+64, rstd_+64, g2, b2, 128, 64, NK);
    stats_kernel<bf16><<<dim3(128, BATCH), 256, 0, stream>>>(h3, sum_+128, sumsq_+128, 128, NK);
    finalize_stats<<<1, 256, 0, stream>>>(sum_+128, sumsq_+128, mean_+128, rstd_+128, 128, 1.f/P4);
    maxpool_kernel<<<BATCH*128*NPTS/256, 256, 0, stream>>>(h3, mean_+128, rstd_+128, g3, b3, cat, 128, 128);

    // layer 4: fused GEMM + stats + raw max/min pooling (no h4 tensor)
    gemm4_fused<<<dim3(P4/64,4), 256, 0, stream>>>(W4, h3, mean_+128, rstd_+128, g3, b3,
                                                   pmax, pmin, sum_+256, sumsq_+256);
    finalize_stats<<<1, 256, 0, stream>>>(sum_+256, sumsq_+256, mean_+256, rstd_+256, 256, 1.f/P4);
    cat4_kernel<<<BATCH*256*NPTS/256, 256, 0, stream>>>(pmax, pmin, mean_+256, rstd_+256, g4, b4, cat);

    // layer 5: 512x512 over B*N columns; cat is already post-activation -> identity BN on load
    gemm_act<float,float><<<dim3(BATCH*NPTS/64,8), 256, 0, stream>>>(W5, cat, out,
        ident, ident+512, ident+1024, ident+1536, 512, 512, NPTS);
    stats_kernel<float><<<dim3(512, BATCH), 256, 0, stream>>>(out, sum_+512, sumsq_+512, 512, NPTS);
    finalize_stats<<<2, 256, 0, stream>>>(sum_+512, sumsq_+512, mean_+512, rstd_+512, 512, 1.f/(BATCH*NPTS));
    final_bn<<<BATCH*EMB*NPTS/256, 256, 0, stream>>>(out, mean_+512, rstd_+512, g5, b5);
}

// Round 4
// 1282.818 us; speedup vs baseline: 4.9937x; 2.6150x over previous
//
#include <hip/hip_runtime.h>
#include <hip/hip_bf16.h>

typedef __hip_bfloat16 bf16;

#define BATCH 8
#define NPTS 2048
#define KNN 20
#define NK (NPTS*KNN)      // 40960
#define P4 (BATCH*NK)      // 327680
#define EMB 512

__device__ __forceinline__ float toF(float v){ return v; }
__device__ __forceinline__ float toF(bf16 v){ return __bfloat162float(v); }
__device__ __forceinline__ void stv(float* p, float v){ *p = v; }
__device__ __forceinline__ void stv(bf16* p, float v){ *p = __float2bfloat16(v); }

// float atomic max/min via integer punning (works for all signs; init -inf/+inf)
__device__ __forceinline__ void atomicMaxF(float* a, float v){
    if (v >= 0.f) atomicMax((int*)a, __float_as_int(v));
    else          atomicMin((unsigned int*)a, (unsigned int)__float_as_int(v));
}
__device__ __forceinline__ void atomicMinF(float* a, float v){
    if (v >= 0.f) atomicMin((int*)a, __float_as_int(v));
    else          atomicMax((unsigned int*)a, (unsigned int)__float_as_int(v));
}

// monotone flip encoding: unsigned compare == float compare (all signs)
__device__ __forceinline__ unsigned int fenc(float f){
    unsigned int b = __float_as_uint(f);
    return (b & 0x80000000u) ? ~b : (b | 0x80000000u);
}
__device__ __forceinline__ float fdec(unsigned int u){
    unsigned int b = (u & 0x80000000u) ? (u & 0x7fffffffu) : ~u;
    return __uint_as_float(b);
}

// ---------------- init: zero sums, set identity-BN params ----------------
__global__ void init_stats(float* sums, float* ident)
{
    int t = blockIdx.x*256 + threadIdx.x;
    if (t < 2048) sums[t] = 0.f;                 // sum[1024] + sumsq[1024]
    if (t < 2048) {
        // ident layout: mean[512]=0, rstd[512]=1, gamma[512]=1, beta[512]=0
        float v = (t < 512) ? 0.f : (t < 1536) ? 1.f : 0.f;
        ident[t] = v;
    }
}

__global__ void zero_shadow(float* shadow)
{
    int t = blockIdx.x*256 + threadIdx.x;        // 8*512 = 4096
    if (t < 4096) shadow[t] = 0.f;
}

__global__ void pool_init(float* pmax, float* pmin)
{
    int t = blockIdx.x*256 + threadIdx.x;        // 8*256*2048 = 4194304 total
    pmax[t] = -3.0e38f;
    pmin[t] =  3.0e38f;
}

// ---------------- KNN: one WAVE per point, register top-20, wave merge ----------------
__global__ __launch_bounds__(256)
void knn_kernel(const float* __restrict__ x, int* __restrict__ idx)
{
    #pragma clang fp contract(off)
    __shared__ float sx[3*NPTS];
    const int b  = blockIdx.x / (NPTS/4);     // 512 blocks per batch
    const int nb = blockIdx.x % (NPTS/4);     // group of 4 points per block
    const float* xb = x + (size_t)b*3*NPTS;
    for (int i = threadIdx.x; i < 3*NPTS; i += 256) sx[i] = xb[i];
    __syncthreads();

    const int wave = threadIdx.x >> 6;
    const int lane = threadIdx.x & 63;
    const int n = nb*4 + wave;

    const float x0 = sx[n], x1 = sx[NPTS+n], x2 = sx[2*NPTS+n];
    const float xxn = x0*x0 + x1*x1 + x2*x2;

    float best[KNN]; int bi[KNN];
    #pragma unroll
    for (int i = 0; i < KNN; ++i) { best[i] = -3e38f; bi[i] = 0x7fffffff; }

    #pragma unroll
    for (int j = 0; j < NPTS/64; ++j) {
        int m = lane + j*64;
        float y0 = sx[m], y1 = sx[NPTS+m], y2 = sx[2*NPTS+m];
        float dot = x0*y0 + x1*y1 + x2*y2;
        float xxm = y0*y0 + y1*y1 + y2*y2;
        float v = -xxn - (-2.f*dot) - xxm;    // same rounding as reference path
        int mi = m;
        #pragma unroll
        for (int i = 0; i < KNN; ++i) {       // branchless sorted insert
            bool sw = v > best[i];
            float tv = sw ? best[i] : v;
            int   ti = sw ? bi[i]   : mi;
            best[i] = sw ? v  : best[i];
            bi[i]   = sw ? mi : bi[i];
            v = tv; mi = ti;
        }
    }

    // wave-wide merge: 20 rounds, pop global (max value, min index)
    size_t obase = ((size_t)b*NPTS + n)*KNN;
    #pragma unroll 1
    for (int s = 0; s < KNN; ++s) {
        float mv = best[0]; int mi = bi[0];
        #pragma unroll
        for (int off = 1; off < 64; off <<= 1) {
            float ov = __shfl_xor(mv, off);
            int   oi = __shfl_xor(mi, off);
            if (ov > mv || (ov == mv && oi < mi)) { mv = ov; mi = oi; }
        }
        bool win = (best[0] == mv) && (bi[0] == mi);
        #pragma unroll
        for (int i = 0; i < KNN-1; ++i) {     // winner shifts its list up
            best[i] = win ? best[i+1] : best[i];
            bi[i]   = win ? bi[i+1]   : bi[i];
        }
        best[KNN-1] = win ? -3e38f      : best[KNN-1];
        bi[KNN-1]   = win ? 0x7fffffff  : bi[KNN-1];
        if (lane == 0) idx[obase + s] = mi;
    }
}

// ---------------- conv1: gather edge features + 6->64 pointwise conv ----------------
__global__ void conv1_kernel(const float* __restrict__ x, const int* __restrict__ idx,
                             const float* __restrict__ W1, bf16* __restrict__ h1)
{
    int p = blockIdx.x*256 + threadIdx.x;
    if (p >= P4) return;
    int b = p / NK;
    int r = p - b*NK;       // n*KNN + kk
    int n = r / KNN;
    int j = idx[p];
    const float* xb = x + (size_t)b*3*NPTS;
    float c0 = xb[n],      c1 = xb[NPTS+n],   c2 = xb[2*NPTS+n];
    float d0 = xb[j]-c0,   d1 = xb[NPTS+j]-c1, d2 = xb[2*NPTS+j]-c2;
    bf16* outp = h1 + (size_t)b*64*NK + r;
    #pragma unroll 8
    for (int o = 0; o < 64; ++o) {
        const float* wr = W1 + o*6;
        float acc = wr[0]*d0 + wr[1]*d1 + wr[2]*d2 + wr[3]*c0 + wr[4]*c1 + wr[5]*c2;
        outp[(size_t)o*NK] = __float2bfloat16(acc);
    }
}

// ---------------- per-channel sum / sumsq (grid = (C, BATCH)) ----------------
template<typename T>
__global__ void stats_kernel(const T* __restrict__ h, float* __restrict__ sum,
                             float* __restrict__ sumsq, int C, int R)
{
    int c = blockIdx.x, b = blockIdx.y;
    const T* hp = h + ((size_t)b*C + c)*R;
    float s = 0.f, ss = 0.f;
    for (int r = threadIdx.x; r < R; r += 256) {
        float v = toF(hp[r]);
        s += v; ss += v*v;
    }
    #pragma unroll
    for (int off = 32; off > 0; off >>= 1) {
        s  += __shfl_down(s, off);
        ss += __shfl_down(ss, off);
    }
    __shared__ float as_[4], bs_[4];
    int w = threadIdx.x >> 6;
    if ((threadIdx.x & 63) == 0) { as_[w] = s; bs_[w] = ss; }
    __syncthreads();
    if (threadIdx.x == 0) {
        atomicAdd(&sum[c],   as_[0]+as_[1]+as_[2]+as_[3]);
        atomicAdd(&sumsq[c], bs_[0]+bs_[1]+bs_[2]+bs_[3]);
    }
}

__global__ void finalize_stats(const float* __restrict__ sum, const float* __restrict__ sumsq,
                               float* __restrict__ mean, float* __restrict__ rstd,
                               int C, float invCnt)
{
    int c = blockIdx.x*256 + threadIdx.x;
    if (c < C) {
        float m = sum[c]*invCnt;
        float var = sumsq[c]*invCnt - m*m;
        mean[c] = m;
        rstd[c] = rsqrtf(var + 1e-5f);
    }
}

// fold 8 shadow copies: shadow layout [8][512] = [8][sum256|sumsq256]
__global__ void finalize_stats8(const float* __restrict__ shadow,
                                float* __restrict__ mean, float* __restrict__ rstd,
                                float invCnt)
{
    int c = threadIdx.x;   // 256 threads, one block
    float s = 0.f, q = 0.f;
    #pragma unroll
    for (int r = 0; r < 8; ++r) { s += shadow[r*512 + c]; q += shadow[r*512 + 256 + c]; }
    float m = s*invCnt;
    float var = q*invCnt - m*m;
    mean[c] = m;
    rstd[c] = rsqrtf(var + 1e-5f);
}

// ---------------- tiled GEMM with BN+ReLU applied to the INPUT on load ----------------
template<typename InT, typename OutT>
__global__ __launch_bounds__(256)
void gemm_act(const float* __restrict__ W, const InT* __restrict__ in,
              OutT* __restrict__ out,
              const float* __restrict__ mean, const float* __restrict__ rstd,
              const float* __restrict__ gamma, const float* __restrict__ beta,
              int Cout, int Cin, int R)
{
    __shared__ float As[16][64];
    __shared__ float Wsm[16][64];
    const int tid = threadIdx.x;
    const int tx = tid & 15, ty = tid >> 4;
    const int colBase = blockIdx.x * 64;
    const int rowBase = blockIdx.y * 64;
    const int b = colBase / R;           // R % 64 == 0 -> tile within one batch
    const int r0 = colBase - b * R;
    const InT* inb = in + (size_t)b * Cin * R;

    float acc[4][4] = {};
    for (int k0 = 0; k0 < Cin; k0 += 16) {
        #pragma unroll
        for (int l = 0; l < 4; ++l) {
            int li = tid + l*256;
            int kk = li >> 6, col = li & 63;
            int c = k0 + kk;
            float v = toF(inb[(size_t)c*R + r0 + col]);
            As[kk][col] = fmaxf(fmaf((v - mean[c]) * rstd[c], gamma[c], beta[c]), 0.f);
        }
        #pragma unroll
        for (int l = 0; l < 4; ++l) {
            int li = tid + l*256;
            int kk = li & 15, row = li >> 4;
            Wsm[kk][row] = W[(size_t)(rowBase + row)*Cin + k0 + kk];
        }
        __syncthreads();
        #pragma unroll
        for (int kk = 0; kk < 16; ++kk) {
            float a0 = As[kk][tx*4+0], a1 = As[kk][tx*4+1], a2 = As[kk][tx*4+2], a3 = As[kk][tx*4+3];
            float w0 = Wsm[kk][ty*4+0], w1 = Wsm[kk][ty*4+1], w2 = Wsm[kk][ty*4+2], w3 = Wsm[kk][ty*4+3];
            acc[0][0] = fmaf(w0,a0,acc[0][0]); acc[0][1] = fmaf(w0,a1,acc[0][1]);
            acc[0][2] = fmaf(w0,a2,acc[0][2]); acc[0][3] = fmaf(w0,a3,acc[0][3]);
            acc[1][0] = fmaf(w1,a0,acc[1][0]); acc[1][1] = fmaf(w1,a1,acc[1][1]);
            acc[1][2] = fmaf(w1,a2,acc[1][2]); acc[1][3] = fmaf(w1,a3,acc[1][3]);
            acc[2][0] = fmaf(w2,a0,acc[2][0]); acc[2][1] = fmaf(w2,a1,acc[2][1]);
            acc[2][2] = fmaf(w2,a2,acc[2][2]); acc[2][3] = fmaf(w2,a3,acc[2][3]);
            acc[3][0] = fmaf(w3,a0,acc[3][0]); acc[3][1] = fmaf(w3,a1,acc[3][1]);
            acc[3][2] = fmaf(w3,a2,acc[3][2]); acc[3][3] = fmaf(w3,a3,acc[3][3]);
        }
        __syncthreads();
    }
    #pragma unroll
    for (int i = 0; i < 4; ++i) {
        size_t obase = ((size_t)b*Cout + rowBase + ty*4 + i)*R + r0 + tx*4;
        stv(&out[obase+0], acc[i][0]);
        stv(&out[obase+1], acc[i][1]);
        stv(&out[obase+2], acc[i][2]);
        stv(&out[obase+3], acc[i][3]);
    }
}

// ---------------- layer-4 GEMM, fused stats + pooling (LDS-local, few atomics) ----------------
__global__ __launch_bounds__(256)
void gemm4_fused(const float* __restrict__ W, const bf16* __restrict__ in,
                 const float* __restrict__ mean, const float* __restrict__ rstd,
                 const float* __restrict__ gamma, const float* __restrict__ beta,
                 float* __restrict__ pmax, float* __restrict__ pmin,
                 float* __restrict__ shadow)
{
    const int Cin = 128, R = NK;
    __shared__ float As[16][64];
    __shared__ float Wsm[16][64];
    __shared__ unsigned int pmxS[64][4];   // flip-encoded block-local pooling
    __shared__ unsigned int pmnS[64][4];
    const int tid = threadIdx.x;
    const int tx = tid & 15, ty = tid >> 4;
    const int colBase = blockIdx.x * 64;
    const int rowBase = blockIdx.y * 64;
    const int b = colBase / R;
    const int r0 = colBase - b * R;
    const bf16* inb = in + (size_t)b * Cin * R;

    // init LDS pool (256 entries per array, 1 per thread)
    pmxS[tid >> 2][tid & 3] = 0u;            // encodes "-inf"
    pmnS[tid >> 2][tid & 3] = 0xFFFFFFFFu;   // encodes "+inf"

    float acc[4][4] = {};
    for (int k0 = 0; k0 < Cin; k0 += 16) {
        #pragma unroll
        for (int l = 0; l < 4; ++l) {
            int li = tid + l*256;
            int kk = li >> 6, col = li & 63;
            int c = k0 + kk;
            float v = __bfloat162float(inb[(size_t)c*R + r0 + col]);
            As[kk][col] = fmaxf(fmaf((v - mean[c]) * rstd[c], gamma[c], beta[c]), 0.f);
        }
        #pragma unroll
        for (int l = 0; l < 4; ++l) {
            int li = tid + l*256;
            int kk = li & 15, row = li >> 4;
            Wsm[kk][row] = W[(size_t)(rowBase + row)*Cin + k0 + kk];
        }
        __syncthreads();
        #pragma unroll
        for (int kk = 0; kk < 16; ++kk) {
            float a0 = As[kk][tx*4+0], a1 = As[kk][tx*4+1], a2 = As[kk][tx*4+2], a3 = As[kk][tx*4+3];
            float w0 = Wsm[kk][ty*4+0], w1 = Wsm[kk][ty*4+1], w2 = Wsm[kk][ty*4+2], w3 = Wsm[kk][ty*4+3];
            acc[0][0] = fmaf(w0,a0,acc[0][0]); acc[0][1] = fmaf(w0,a1,acc[0][1]);
            acc[0][2] = fmaf(w0,a2,acc[0][2]); acc[0][3] = fmaf(w0,a3,acc[0][3]);
            acc[1][0] = fmaf(w1,a0,acc[1][0]); acc[1][1] = fmaf(w1,a1,acc[1][1]);
            acc[1][2] = fmaf(w1,a2,acc[1][2]); acc[1][3] = fmaf(w1,a3,acc[1][3]);
            acc[2][0] = fmaf(w2,a0,acc[2][0]); acc[2][1] = fmaf(w2,a1,acc[2][1]);
            acc[2][2] = fmaf(w2,a2,acc[2][2]); acc[2][3] = fmaf(w2,a3,acc[2][3]);
            acc[3][0] = fmaf(w3,a0,acc[3][0]); acc[3][1] = fmaf(w3,a1,acc[3][1]);
            acc[3][2] = fmaf(w3,a2,acc[3][2]); acc[3][3] = fmaf(w3,a3,acc[3][3]);
        }
        __syncthreads();
    }

    // ---- fused stats: reduce across 16 tx lanes, then shadow atomicAdd ----
    float* sh = shadow + (size_t)(blockIdx.x & 7) * 512;
    #pragma unroll
    for (int i = 0; i < 4; ++i) {
        float s  = acc[i][0]+acc[i][1]+acc[i][2]+acc[i][3];
        float q  = acc[i][0]*acc[i][0]+acc[i][1]*acc[i][1]+acc[i][2]*acc[i][2]+acc[i][3]*acc[i][3];
        #pragma unroll
        for (int off = 1; off < 16; off <<= 1) {
            s += __shfl_xor(s, off);
            q += __shfl_xor(q, off);
        }
        if (tx == 0) {
            int c = rowBase + ty*4 + i;   // c in [0,256)
            atomicAdd(&sh[c], s);
            atomicAdd(&sh[256 + c], q);
        }
    }

    // ---- block-local pooling into LDS (flip-encoded uint atomics) ----
    const int n0 = r0 / KNN;
    {
        int rr = r0 + tx*4;
        #pragma unroll
        for (int i = 0; i < 4; ++i) {
            int cl = ty*4 + i;
            int n = rr / KNN;
            float mx = acc[i][0], mn = acc[i][0];
            #pragma unroll
            for (int j = 1; j < 4; ++j) {
                int nj = (rr + j) / KNN;
                if (nj != n) {
                    atomicMax(&pmxS[cl][n-n0], fenc(mx));
                    atomicMin(&pmnS[cl][n-n0], fenc(mn));
                    n = nj; mx = acc[i][j]; mn = acc[i][j];
                } else {
                    mx = fmaxf(mx, acc[i][j]); mn = fminf(mn, acc[i][j]);
                }
            }
            atomicMax(&pmxS[cl][n-n0], fenc(mx));
            atomicMin(&pmnS[cl][n-n0], fenc(mn));
        }
    }
    __syncthreads();

    // ---- flush: interior n-groups = plain store; boundary = global atomic ----
    {
        int cl = tid >> 2, nl = tid & 3;
        int n = n0 + nl;
        int gfirst = n*KNN, glast = gfirst + KNN - 1;
        if (gfirst <= r0 + 63 && glast >= r0) {
            int c = rowBase + cl;
            float vmx = fdec(pmxS[cl][nl]);
            float vmn = fdec(pmnS[cl][nl]);
            float* pmaxc = pmax + ((size_t)b*256 + c)*NPTS + n;
            float* pminc = pmin + ((size_t)b*256 + c)*NPTS + n;
            if (gfirst >= r0 && glast <= r0 + 63) {
                *pmaxc = vmx;
                *pminc = vmn;
            } else {
                atomicMaxF(pmaxc, vmx);
                atomicMinF(pminc, vmn);
            }
        }
    }
}

// ---------------- layer-4 pooled values -> BN+ReLU -> cat[256:512] ----------------
__global__ void cat4_kernel(const float* __restrict__ pmax, const float* __restrict__ pmin,
                            const float* __restrict__ mean, const float* __restrict__ rstd,
                            const float* __restrict__ g, const float* __restrict__ be,
                            float* __restrict__ cat)
{
    int t = blockIdx.x*256 + threadIdx.x;   // < 8*256*2048
    int n = t & (NPTS-1);
    int c = (t >> 11) & 255;
    int b = t >> 19;
    float gg = g[c];
    float v = (gg >= 0.f) ? pmax[t] : pmin[t];
    cat[((size_t)b*512 + 256 + c)*NPTS + n] =
        fmaxf(fmaf((v - mean[c])*rstd[c], gg, be[c]), 0.f);
}

// ---------------- k-maxpool of bn+relu'd h into cat (layers 1-3) ----------------
__global__ void maxpool_kernel(const bf16* __restrict__ h,
                               const float* __restrict__ mean, const float* __restrict__ rstd,
                               const float* __restrict__ g, const float* __restrict__ be,
                               float* __restrict__ cat, int C, int coff)
{
    int t = blockIdx.x*256 + threadIdx.x;
    if (t >= BATCH*C*NPTS) return;
    int n = t & (NPTS-1);
    int tmp = t >> 11;
    int c = tmp % C;
    int b = tmp / C;
    const bf16* src = h + ((size_t)(b*C + c)*NPTS + n)*KNN;
    float m = mean[c], rs = rstd[c], gg = g[c], bb = be[c];
    float best = -3e38f;
    #pragma unroll
    for (int kk = 0; kk < KNN; ++kk) {
        float v = __bfloat162float(src[kk]);
        best = fmaxf(best, fmaf((v - m)*rs, gg, bb));
    }
    cat[((size_t)b*512 + coff + c)*NPTS + n] = fmaxf(best, 0.f);
}

// ---------------- final BN+ReLU in place on d_out ----------------
__global__ void final_bn(float* __restrict__ out,
                         const float* __restrict__ mean, const float* __restrict__ rstd,
                         const float* __restrict__ g, const float* __restrict__ be)
{
    int t = blockIdx.x*256 + threadIdx.x;
    if (t >= BATCH*EMB*NPTS) return;
    int c = (t >> 11) & 511;
    float v = out[t];
    out[t] = fmaxf(fmaf((v - mean[c])*rstd[c], g[c], be[c]), 0.f);
}

extern "C" void kernel_launch(void* const* d_in, const int* in_sizes, int n_in,
                              void* d_out, int out_size, void* d_ws, size_t ws_size,
                              hipStream_t stream)
{
    const float* x  = (const float*)d_in[0];
    const float* W1 = (const float*)d_in[2];
    const float* W2 = (const float*)d_in[3];
    const float* W3 = (const float*)d_in[4];
    const float* W4 = (const float*)d_in[5];
    const float* W5 = (const float*)d_in[6];
    const float* g1 = (const float*)d_in[7];  const float* b1 = (const float*)d_in[8];
    const float* g2 = (const float*)d_in[9];  const float* b2 = (const float*)d_in[10];
    const float* g3 = (const float*)d_in[11]; const float* b3 = (const float*)d_in[12];
    const float* g4 = (const float*)d_in[13]; const float* b4 = (const float*)d_in[14];
    const float* g5 = (const float*)d_in[15]; const float* b5 = (const float*)d_in[16];
    float* out = (float*)d_out;

    // workspace layout (~193 MiB + 16KB shadow):
    //   idx 1.31MB | stats 24KB | region1 42MB (h1, later pmax/pmin 2x16.8MB)
    //   | h2 42MB | h3 84MB | cat 33.5MB | shadow 16KB
    char* w = (char*)d_ws;
    int*   idx    = (int*)w;
    float* st_    = (float*)(w + 1310720);
    float* sum_   = st_;
    float* sumsq_ = st_ + 1024;
    float* mean_  = st_ + 2048;
    float* rstd_  = st_ + 3072;
    float* ident  = st_ + 4096;   // mean/rstd/gamma/beta x 512
    bf16*  h1     = (bf16*)(w + 1335296);
    float* pmax   = (float*)h1;                       // aliases h1 after it's dead
    float* pmin   = pmax + (size_t)BATCH*256*NPTS;    // +16.78MB
    bf16*  h2     = (bf16*)(w + 1335296 + 41943040);
    bf16*  h3     = (bf16*)(w + 1335296 + 41943040 + 41943040);
    float* cat    = (float*)(w + 1335296 + 41943040 + 41943040 + 83886080);
    float* shadow = (float*)(w + 1335296 + 41943040 + 41943040 + 83886080 + 33554432);

    init_stats<<<8, 256, 0, stream>>>(sum_, ident);
    zero_shadow<<<16, 256, 0, stream>>>(shadow);
    knn_kernel<<<BATCH*NPTS/4, 256, 0, stream>>>(x, idx);
    conv1_kernel<<<P4/256, 256, 0, stream>>>(x, idx, W1, h1);

    // layer 1 stats + maxpool
    stats_kernel<bf16><<<dim3(64, BATCH), 256, 0, stream>>>(h1, sum_, sumsq_, 64, NK);
    finalize_stats<<<1, 256, 0, stream>>>(sum_, sumsq_, mean_, rstd_, 64, 1.f/P4);
    maxpool_kernel<<<BATCH*64*NPTS/256, 256, 0, stream>>>(h1, mean_, rstd_, g1, b1, cat, 64, 0);

    // layer 2 (reads h1 -> h1 is dead afterwards)
    gemm_act<bf16,bf16><<<dim3(P4/64,1), 256, 0, stream>>>(W2, h1, h2, mean_, rstd_, g1, b1, 64, 64, NK);
    pool_init<<<BATCH*256*NPTS/256, 256, 0, stream>>>(pmax, pmin);   // aliases h1, AFTER gemm2
    stats_kernel<bf16><<<dim3(64, BATCH), 256, 0, stream>>>(h2, sum_+64, sumsq_+64, 64, NK);
    finalize_stats<<<1, 256, 0, stream>>>(sum_+64, sumsq_+64, mean_+64, rstd_+64, 64, 1.f/P4);
    maxpool_kernel<<<BATCH*64*NPTS/256, 256, 0, stream>>>(h2, mean_+64, rstd_+64, g2, b2, cat, 64, 64);

    // layer 3
    gemm_act<bf16,bf16><<<dim3(P4/64,2), 256, 0, stream>>>(W3, h2, h3, mean_+64, rstd_+64, g2, b2, 128, 64, NK);
    stats_kernel<bf16><<<dim3(128, BATCH), 256, 0, stream>>>(h3, sum_+128, sumsq_+128, 128, NK);
    finalize_stats<<<1, 256, 0, stream>>>(sum_+128, sumsq_+128, mean_+128, rstd_+128, 128, 1.f/P4);
    maxpool_kernel<<<BATCH*128*NPTS/256, 256, 0, stream>>>(h3, mean_+128, rstd_+128, g3, b3, cat, 128, 128);

    // layer 4: fused GEMM + shadow stats + LDS-local pooling (no h4 tensor)
    gemm4_fused<<<dim3(P4/64,4), 256, 0, stream>>>(W4, h3, mean_+128, rstd_+128, g3, b3,
                                                   pmax, pmin, shadow);
    finalize_stats8<<<1, 256, 0, stream>>>(shadow, mean_+256, rstd_+256, 1.f/P4);
    cat4_kernel<<<BATCH*256*NPTS/256, 256, 0, stream>>>(pmax, pmin, mean_+256, rstd_+256, g4, b4, cat);

    // layer 5: 512x512 over B*N columns; cat is already post-activation -> identity BN on load
    gemm_act<float,float><<<dim3(BATCH*NPTS/64,8), 256, 0, stream>>>(W5, cat, out,
        ident, ident+512, ident+1024, ident+1536, 512, 512, NPTS);
    stats_kernel<float><<<dim3(512, BATCH), 256, 0, stream>>>(out, sum_+512, sumsq_+512, 512, NPTS);
    finalize_stats<<<2, 256, 0, stream>>>(sum_+512, sumsq_+512, mean_+512, rstd_+512, 512, 1.f/(BATCH*NPTS));
    final_bn<<<BATCH*EMB*NPTS/256, 256, 0, stream>>>(out, mean_+512, rstd_+512, g5, b5);
}

// Round 5
// 583.647 us; speedup vs baseline: 10.9758x; 2.1979x over previous
//
#include <hip/hip_runtime.h>
#include <hip/hip_bf16.h>

typedef __hip_bfloat16 bf16;
typedef __attribute__((ext_vector_type(8))) short short8v;
typedef __attribute__((ext_vector_type(4))) float f32x4;
typedef unsigned int uint;

#define BATCH 8
#define NPTS 2048
#define KNN 20
#define NK (NPTS*KNN)      // 40960
#define P4 (BATCH*NK)      // 327680
#define BN_TOT (BATCH*NPTS) // 16384

union BU { bf16 h; unsigned short u; };
__device__ __forceinline__ unsigned short f2bf(float f){
    BU bu; bu.h = __float2bfloat16(f); return bu.u;
}
__device__ __forceinline__ float bfu2f(unsigned short u){
    return __uint_as_float(((uint)u) << 16);
}

// float atomic max/min via integer punning (init -inf/+inf)
__device__ __forceinline__ void atomicMaxF(float* a, float v){
    if (v >= 0.f) atomicMax((int*)a, __float_as_int(v));
    else          atomicMin((unsigned int*)a, (unsigned int)__float_as_int(v));
}
__device__ __forceinline__ void atomicMinF(float* a, float v){
    if (v >= 0.f) atomicMin((int*)a, __float_as_int(v));
    else          atomicMax((unsigned int*)a, (unsigned int)__float_as_int(v));
}
// monotone flip encoding: unsigned compare == float compare
__device__ __forceinline__ uint fenc(float f){
    uint b = __float_as_uint(f);
    return (b & 0x80000000u) ? ~b : (b | 0x80000000u);
}
__device__ __forceinline__ float fdec(uint u){
    uint b = (u & 0x80000000u) ? (u & 0x7fffffffu) : ~u;
    return __uint_as_float(b);
}

// ---------------- init: zero shadow stats, identity scbi for layer-5 input ----------------
__global__ void initK(float* __restrict__ shadow, uint* __restrict__ scbiU5)
{
    int t = blockIdx.x*256 + threadIdx.x;
    if (t < 5*16*1024) shadow[t] = 0.f;
    if (t < 512) scbiU5[t] = 0x00003F80u;   // sc=1.0bf16, bi=0
}

__global__ void poolInit(float* __restrict__ pmax, float* __restrict__ pmin)
{
    int t = blockIdx.x*256 + threadIdx.x;   // 4,194,304 total
    pmax[t] = -3e38f; pmin[t] = 3e38f;
}

__global__ void cvtW(const float* __restrict__ src, short* __restrict__ dst, int n)
{
    int t = blockIdx.x*256 + threadIdx.x;
    if (t < n) dst[t] = (short)f2bf(src[t]);
}

// ---------------- KNN (unchanged, verified) ----------------
__global__ __launch_bounds__(256)
void knn_kernel(const float* __restrict__ x, int* __restrict__ idx)
{
    #pragma clang fp contract(off)
    __shared__ float sx[3*NPTS];
    const int b  = blockIdx.x / (NPTS/4);
    const int nb = blockIdx.x % (NPTS/4);
    const float* xb = x + (size_t)b*3*NPTS;
    for (int i = threadIdx.x; i < 3*NPTS; i += 256) sx[i] = xb[i];
    __syncthreads();

    const int wave = threadIdx.x >> 6;
    const int lane = threadIdx.x & 63;
    const int n = nb*4 + wave;

    const float x0 = sx[n], x1 = sx[NPTS+n], x2 = sx[2*NPTS+n];
    const float xxn = x0*x0 + x1*x1 + x2*x2;

    float best[KNN]; int bi[KNN];
    #pragma unroll
    for (int i = 0; i < KNN; ++i) { best[i] = -3e38f; bi[i] = 0x7fffffff; }

    #pragma unroll
    for (int j = 0; j < NPTS/64; ++j) {
        int m = lane + j*64;
        float y0 = sx[m], y1 = sx[NPTS+m], y2 = sx[2*NPTS+m];
        float dot = x0*y0 + x1*y1 + x2*y2;
        float xxm = y0*y0 + y1*y1 + y2*y2;
        float v = -xxn - (-2.f*dot) - xxm;
        int mi = m;
        #pragma unroll
        for (int i = 0; i < KNN; ++i) {
            bool sw = v > best[i];
            float tv = sw ? best[i] : v;
            int   ti = sw ? bi[i]   : mi;
            best[i] = sw ? v  : best[i];
            bi[i]   = sw ? mi : bi[i];
            v = tv; mi = ti;
        }
    }
    size_t obase = ((size_t)b*NPTS + n)*KNN;
    #pragma unroll 1
    for (int s = 0; s < KNN; ++s) {
        float mv = best[0]; int mi = bi[0];
        #pragma unroll
        for (int off = 1; off < 64; off <<= 1) {
            float ov = __shfl_xor(mv, off);
            int   oi = __shfl_xor(mi, off);
            if (ov > mv || (ov == mv && oi < mi)) { mv = ov; mi = oi; }
        }
        bool win = (best[0] == mv) && (bi[0] == mi);
        #pragma unroll
        for (int i = 0; i < KNN-1; ++i) {
            best[i] = win ? best[i+1] : best[i];
            bi[i]   = win ? bi[i+1]   : bi[i];
        }
        best[KNN-1] = win ? -3e38f     : best[KNN-1];
        bi[KNN-1]   = win ? 0x7fffffff : bi[KNN-1];
        if (lane == 0) idx[obase + s] = mi;
    }
}

// ---------------- conv1: edge features + 6->64 conv, r-major output ----------------
__global__ void conv1T(const float* __restrict__ x, const int* __restrict__ idx,
                       const float* __restrict__ W1, bf16* __restrict__ h1)
{
    int p = blockIdx.x*256 + threadIdx.x;   // flat row br
    int b = p / NK;
    int r = p - b*NK;
    int n = r / KNN;
    int j = idx[p];
    const float* xb = x + (size_t)b*3*NPTS;
    float c0 = xb[n], c1 = xb[NPTS+n], c2 = xb[2*NPTS+n];
    float d0 = xb[j]-c0, d1 = xb[NPTS+j]-c1, d2 = xb[2*NPTS+j]-c2;
    uint4* outp = reinterpret_cast<uint4*>(reinterpret_cast<unsigned short*>(h1) + (size_t)p*64);
    #pragma unroll
    for (int ch = 0; ch < 8; ++ch) {
        uint u[4];
        #pragma unroll
        for (int q = 0; q < 4; ++q) {
            const float* wa = W1 + (ch*8 + q*2)*6;
            float a0 = wa[0]*d0 + wa[1]*d1 + wa[2]*d2 + wa[3]*c0 + wa[4]*c1 + wa[5]*c2;
            const float* wb = wa + 6;
            float a1 = wb[0]*d0 + wb[1]*d1 + wb[2]*d2 + wb[3]*c0 + wb[4]*c1 + wb[5]*c2;
            u[q] = (uint)f2bf(a0) | ((uint)f2bf(a1) << 16);
        }
        outp[ch] = make_uint4(u[0], u[1], u[2], u[3]);
    }
}

// ---------------- layer-1 stats on r-major h1 ----------------
__global__ void statsT64(const bf16* __restrict__ h, float* __restrict__ shadow)
{
    __shared__ float ls[4][64], lq[4][64];
    int t = threadIdx.x;
    int c = t & 63, grp = t >> 6;
    const unsigned short* hp = reinterpret_cast<const unsigned short*>(h);
    size_t base = (size_t)blockIdx.x*1024;
    float s = 0.f, q = 0.f;
    for (int it = 0; it < 256; ++it) {
        size_t br = base + grp + (size_t)it*4;
        float v = bfu2f(hp[br*64 + c]);
        s += v; q += v*v;
    }
    ls[grp][c] = s; lq[grp][c] = q;
    __syncthreads();
    if (t < 64) {
        float S = ls[0][t]+ls[1][t]+ls[2][t]+ls[3][t];
        float Q = lq[0][t]+lq[1][t]+lq[2][t]+lq[3][t];
        float* sh = shadow + (size_t)(blockIdx.x & 15)*1024;
        atomicAdd(&sh[t], S);
        atomicAdd(&sh[512 + t], Q);
    }
}

// ---------------- fold shadows -> mean/rstd -> (sc,bi) in bf16-pack + f32 ----------------
__global__ void fin_kernel(const float* __restrict__ shadow,
                           const float* __restrict__ gamma, const float* __restrict__ beta,
                           uint* __restrict__ scbiU, float* __restrict__ scbiF,
                           int C, float invCnt)
{
    for (int c = threadIdx.x; c < C; c += 256) {
        float s = 0.f, q = 0.f;
        #pragma unroll
        for (int i = 0; i < 16; ++i) { s += shadow[i*1024 + c]; q += shadow[i*1024 + 512 + c]; }
        float m = s*invCnt;
        float var = q*invCnt - m*m;
        float rs = rsqrtf(var + 1e-5f);
        float sc = rs * gamma[c];
        float bi = fmaf(-m, sc, beta[c]);
        scbiF[2*c] = sc; scbiF[2*c+1] = bi;
        scbiU[c] = ((uint)f2bf(bi) << 16) | (uint)f2bf(sc);
    }
}

// ---------------- MFMA GEMM: out[br][co] = sum_ci W[co][ci] * relu(in[br][ci]*sc+bi) ----------------
// r-major in/out; per-block 64 rows, full Cout; fused stats; optional fused k-pooling (layer 4).
template<int Cout, int Cin, int POOL>
__global__ __launch_bounds__(256)
void gemmT(const short* __restrict__ Wb, const bf16* __restrict__ in,
           const uint* __restrict__ scbi, bf16* __restrict__ outT,
           float* __restrict__ shadow, float* __restrict__ pmax, float* __restrict__ pmin)
{
    constexpr int NT = Cout/16, KS = Cin/32;
    const int tid = threadIdx.x;
    const int lane = tid & 63;
    const int g = lane >> 4, mr = lane & 15;
    const size_t brW = (size_t)blockIdx.x*64 + (size_t)(tid>>6)*16;

    __shared__ uint pmx[5*256], pmn[5*256];
    const int gblk0 = (blockIdx.x*64)/KNN;
    int ng = 0;
    if (POOL) {
        ng = (blockIdx.x*64 + 63)/KNN - gblk0 + 1;
        for (int e = tid; e < 5*256; e += 256){ pmx[e] = 0u; pmn[e] = 0xFFFFFFFFu; }
        __syncthreads();
    }

    f32x4 acc[NT];
    #pragma unroll
    for (int i = 0; i < NT; ++i) acc[i] = (f32x4){0.f,0.f,0.f,0.f};

    const short* inS = reinterpret_cast<const short*>(in);
    for (int ks = 0; ks < KS; ++ks) {
        const int k0 = ks*32 + 8*g;
        const uint4* sp = reinterpret_cast<const uint4*>(scbi + k0);
        uint4 s0 = sp[0], s1 = sp[1];
        uint se[8] = {s0.x, s0.y, s0.z, s0.w, s1.x, s1.y, s1.z, s1.w};
        short8v araw = *reinterpret_cast<const short8v*>(inS + (brW + mr)*Cin + k0);
        short8v a;
        #pragma unroll
        for (int e = 0; e < 8; ++e) {
            float v  = __uint_as_float(((uint)(unsigned short)araw[e]) << 16);
            float sc = __uint_as_float(se[e] << 16);
            float bi = __uint_as_float(se[e] & 0xffff0000u);
            a[e] = (short)f2bf(fmaxf(fmaf(v, sc, bi), 0.f));
        }
        #pragma unroll
        for (int nt = 0; nt < NT; ++nt) {
            short8v bfr = *reinterpret_cast<const short8v*>(Wb + (size_t)(nt*16 + mr)*Cin + k0);
            acc[nt] = __builtin_amdgcn_mfma_f32_16x16x32_bf16(a, bfr, acc[nt], 0, 0, 0);
        }
    }

    if (!POOL) {
        #pragma unroll
        for (int nt = 0; nt < NT; ++nt)
        #pragma unroll
        for (int j = 0; j < 4; ++j) {
            size_t row = brW + (size_t)(g*4 + j);
            outT[row*Cout + nt*16 + mr] = __float2bfloat16(acc[nt][j]);
        }
    } else {
        const int brow = (int)brW + g*4;   // flat row of j=0
        #pragma unroll
        for (int nt = 0; nt < NT; ++nt) {
            int c = nt*16 + mr;
            int gcur = brow / KNN;
            float mx = acc[nt][0], mn = acc[nt][0];
            #pragma unroll
            for (int j = 1; j < 4; ++j) {
                int gj = (brow + j) / KNN;
                if (gj != gcur) {
                    atomicMax(&pmx[(gcur-gblk0)*256 + c], fenc(mx));
                    atomicMin(&pmn[(gcur-gblk0)*256 + c], fenc(mn));
                    gcur = gj; mx = acc[nt][j]; mn = acc[nt][j];
                } else { mx = fmaxf(mx, acc[nt][j]); mn = fminf(mn, acc[nt][j]); }
            }
            atomicMax(&pmx[(gcur-gblk0)*256 + c], fenc(mx));
            atomicMin(&pmn[(gcur-gblk0)*256 + c], fenc(mn));
        }
    }

    // fused per-channel stats
    float* sh = shadow + (size_t)(blockIdx.x & 15)*1024;
    #pragma unroll
    for (int nt = 0; nt < NT; ++nt) {
        float s = acc[nt][0]+acc[nt][1]+acc[nt][2]+acc[nt][3];
        float q = acc[nt][0]*acc[nt][0]+acc[nt][1]*acc[nt][1]
                + acc[nt][2]*acc[nt][2]+acc[nt][3]*acc[nt][3];
        s += __shfl_xor(s, 16); s += __shfl_xor(s, 32);
        q += __shfl_xor(q, 16); q += __shfl_xor(q, 32);
        if (g == 0) {
            atomicAdd(&sh[nt*16 + mr], s);
            atomicAdd(&sh[512 + nt*16 + mr], q);
        }
    }

    if (POOL) {
        __syncthreads();
        const int b0 = blockIdx.x*64, b1 = b0 + 63;
        for (int e = tid; e < ng*256; e += 256) {
            int gl = e >> 8, c = e & 255;
            int grp = gblk0 + gl;            // == flat bn index
            int rfirst = grp*KNN, rlast = rfirst + KNN - 1;
            float vmx = fdec(pmx[e]), vmn = fdec(pmn[e]);
            float* pa = pmax + (size_t)grp*256 + c;
            float* pb = pmin + (size_t)grp*256 + c;
            if (rfirst >= b0 && rlast <= b1) { *pa = vmx; *pb = vmn; }
            else { atomicMaxF(pa, vmx); atomicMinF(pb, vmn); }
        }
    }
}

// ---------------- k-maxpool (bn+relu on the fly) into cat_T ----------------
template<int C>
__global__ void maxpoolT(const bf16* __restrict__ h, const float* __restrict__ scbiF,
                         bf16* __restrict__ catT, int coff)
{
    constexpr int PB = 256/C;
    int t = threadIdx.x;
    int c = t & (C-1);
    int bn = blockIdx.x*PB + t/C;
    float sc = scbiF[2*c], bi = scbiF[2*c+1];
    const unsigned short* src = reinterpret_cast<const unsigned short*>(h) + (size_t)bn*KNN*C + c;
    float best = -3e38f;
    #pragma unroll
    for (int kk = 0; kk < KNN; ++kk)
        best = fmaxf(best, fmaf(bfu2f(src[kk*C]), sc, bi));
    catT[(size_t)bn*512 + coff + c] = __float2bfloat16(fmaxf(best, 0.f));
}

// ---------------- layer-4 pooled raw -> BN+ReLU -> cat_T[256:512] ----------------
__global__ void cat4T(const float* __restrict__ pmax, const float* __restrict__ pmin,
                      const float* __restrict__ scbiF, const float* __restrict__ g4,
                      bf16* __restrict__ catT)
{
    int t = blockIdx.x*256 + threadIdx.x;   // bn*256 + c
    int c = t & 255, bn = t >> 8;
    float sc = scbiF[2*c], bi = scbiF[2*c+1];
    float v = (g4[c] >= 0.f) ? pmax[t] : pmin[t];
    catT[(size_t)bn*512 + 256 + c] = __float2bfloat16(fmaxf(fmaf(v, sc, bi), 0.f));
}

// ---------------- final BN+ReLU + transpose to [b][c][n] fp32 ----------------
__global__ void finalT(const bf16* __restrict__ h5, const float* __restrict__ scbiF,
                       float* __restrict__ out)
{
    __shared__ float ls[64][65];
    int t = threadIdx.x;
    int b = blockIdx.z, n0 = blockIdx.x*64, c0 = blockIdx.y*64;
    int j = t & 63, i0 = t >> 6;
    float sc = scbiF[2*(c0+j)], bi = scbiF[2*(c0+j)+1];
    const unsigned short* hp = reinterpret_cast<const unsigned short*>(h5);
    for (int it = 0; it < 16; ++it) {
        int i = i0 + it*4;
        float v = bfu2f(hp[((size_t)(b*NPTS + n0 + i))*512 + c0 + j]);
        ls[i][j] = fmaxf(fmaf(v, sc, bi), 0.f);
    }
    __syncthreads();
    for (int it = 0; it < 16; ++it) {
        int cr = i0 + it*4;
        out[((size_t)b*512 + c0 + cr)*NPTS + n0 + j] = ls[j][cr];
    }
}

extern "C" void kernel_launch(void* const* d_in, const int* in_sizes, int n_in,
                              void* d_out, int out_size, void* d_ws, size_t ws_size,
                              hipStream_t stream)
{
    const float* x  = (const float*)d_in[0];
    const float* W2 = (const float*)d_in[3];
    const float* W3 = (const float*)d_in[4];
    const float* W4 = (const float*)d_in[5];
    const float* W5 = (const float*)d_in[6];
    const float* W1 = (const float*)d_in[2];
    const float* g1 = (const float*)d_in[7];  const float* b1 = (const float*)d_in[8];
    const float* g2 = (const float*)d_in[9];  const float* b2 = (const float*)d_in[10];
    const float* g3 = (const float*)d_in[11]; const float* b3 = (const float*)d_in[12];
    const float* g4 = (const float*)d_in[13]; const float* b4 = (const float*)d_in[14];
    const float* g5 = (const float*)d_in[15]; const float* b5 = (const float*)d_in[16];
    float* out = (float*)d_out;

    // workspace layout (~178 MiB):
    char* w = (char*)d_ws;
    int*   idx    = (int*)w;                          // 1,310,720 B
    uint*  scbiU  = (uint*)(w + 1310720);             // [6][512] u32
    float* scbiF  = (float*)(w + 1323008);            // [5][512][2] f32
    float* shadow = (float*)(w + 1343488);            // [5][16][1024] f32
    short* Wb     = (short*)(w + 1671168);            // bf16 weights, 307200 elems
    bf16*  h1     = (bf16*)(w + 2285568);             // [P4][64]   42MB
    float* pmax   = (float*)h1;                       // alias h1 (dead) [16384][256]
    float* pmin   = pmax + (size_t)BN_TOT*256;
    bf16*  h2     = (bf16*)(w + 44228608);            // [P4][64]   42MB
    bf16*  h5     = h2;                               // alias h2 (dead) [16384][512]
    bf16*  h3     = (bf16*)(w + 86171648);            // [P4][128]  84MB
    bf16*  catT   = (bf16*)(w + 170057728);           // [16384][512] 16.8MB

    short* Wb2 = Wb, *Wb3 = Wb + 4096, *Wb4 = Wb + 12288, *Wb5 = Wb + 45056;
    float* sh1 = shadow, *sh2 = shadow + 16384, *sh3 = shadow + 2*16384,
         * sh4 = shadow + 3*16384, *sh5 = shadow + 4*16384;

    initK<<<320, 256, 0, stream>>>(shadow, scbiU + 5*512);
    cvtW<<<16,   256, 0, stream>>>(W2, Wb2, 4096);
    cvtW<<<32,   256, 0, stream>>>(W3, Wb3, 8192);
    cvtW<<<128,  256, 0, stream>>>(W4, Wb4, 32768);
    cvtW<<<1024, 256, 0, stream>>>(W5, Wb5, 262144);

    knn_kernel<<<BATCH*NPTS/4, 256, 0, stream>>>(x, idx);
    conv1T<<<P4/256, 256, 0, stream>>>(x, idx, W1, h1);

    statsT64<<<320, 256, 0, stream>>>(h1, sh1);
    fin_kernel<<<1, 256, 0, stream>>>(sh1, g1, b1, scbiU, scbiF, 64, 1.f/P4);
    maxpoolT<64><<<BN_TOT/4, 256, 0, stream>>>(h1, scbiF, catT, 0);

    gemmT<64,64,0><<<P4/64, 256, 0, stream>>>(Wb2, h1, scbiU, h2, sh2, nullptr, nullptr);
    fin_kernel<<<1, 256, 0, stream>>>(sh2, g2, b2, scbiU + 512, scbiF + 1024, 64, 1.f/P4);
    maxpoolT<64><<<BN_TOT/4, 256, 0, stream>>>(h2, scbiF + 1024, catT, 64);

    gemmT<128,64,0><<<P4/64, 256, 0, stream>>>(Wb3, h2, scbiU + 512, h3, sh3, nullptr, nullptr);
    fin_kernel<<<1, 256, 0, stream>>>(sh3, g3, b3, scbiU + 1024, scbiF + 2048, 128, 1.f/P4);
    maxpoolT<128><<<BN_TOT/2, 256, 0, stream>>>(h3, scbiF + 2048, catT, 128);

    poolInit<<<BN_TOT*256/256, 256, 0, stream>>>(pmax, pmin);   // h1 dead now
    gemmT<256,128,1><<<P4/64, 256, 0, stream>>>(Wb4, h3, scbiU + 1024, nullptr, sh4, pmax, pmin);
    fin_kernel<<<1, 256, 0, stream>>>(sh4, g4, b4, scbiU + 1536, scbiF + 3072, 256, 1.f/P4);
    cat4T<<<BN_TOT, 256, 0, stream>>>(pmax, pmin, scbiF + 3072, g4, catT);

    gemmT<512,512,0><<<BN_TOT/64, 256, 0, stream>>>(Wb5, catT, scbiU + 5*512, h5, sh5, nullptr, nullptr);
    fin_kernel<<<1, 256, 0, stream>>>(sh5, g5, b5, scbiU + 2048, scbiF + 4096, 512, 1.f/BN_TOT);
    finalT<<<dim3(NPTS/64, 8, BATCH), 256, 0, stream>>>(h5, scbiF + 4096, out);
}

// Round 6
// 536.396 us; speedup vs baseline: 11.9426x; 1.0881x over previous
//
#include <hip/hip_runtime.h>
#include <hip/hip_bf16.h>

typedef __hip_bfloat16 bf16;
typedef __attribute__((ext_vector_type(8))) short short8v;
typedef __attribute__((ext_vector_type(4))) float f32x4;
typedef unsigned int uint;

#define BATCH 8
#define NPTS 2048
#define KNN 20
#define NK (NPTS*KNN)      // 40960
#define P4 (BATCH*NK)      // 327680
#define BN_TOT (BATCH*NPTS) // 16384

union BU { bf16 h; unsigned short u; };
__device__ __forceinline__ unsigned short f2bf(float f){
    BU bu; bu.h = __float2bfloat16(f); return bu.u;
}
__device__ __forceinline__ float bfu2f(unsigned short u){
    return __uint_as_float(((uint)u) << 16);
}

// float atomic max/min via integer punning (init -inf/+inf)
__device__ __forceinline__ void atomicMaxF(float* a, float v){
    if (v >= 0.f) atomicMax((int*)a, __float_as_int(v));
    else          atomicMin((unsigned int*)a, (unsigned int)__float_as_int(v));
}
__device__ __forceinline__ void atomicMinF(float* a, float v){
    if (v >= 0.f) atomicMin((int*)a, __float_as_int(v));
    else          atomicMax((unsigned int*)a, (unsigned int)__float_as_int(v));
}
// monotone flip encoding: unsigned compare == float compare
__device__ __forceinline__ uint fenc(float f){
    uint b = __float_as_uint(f);
    return (b & 0x80000000u) ? ~b : (b | 0x80000000u);
}
__device__ __forceinline__ float fdec(uint u){
    uint b = (u & 0x80000000u) ? (u & 0x7fffffffu) : ~u;
    return __uint_as_float(b);
}

// ---------------- init: zero shadow stats, identity scbi for layer-5 input ----------------
__global__ void initK(float* __restrict__ shadow, uint* __restrict__ scbiU5)
{
    int t = blockIdx.x*256 + threadIdx.x;
    if (t < 5*16*1024) shadow[t] = 0.f;
    if (t < 512) scbiU5[t] = 0x00003F80u;   // sc=1.0bf16, bi=0
}

__global__ void poolInit(float* __restrict__ pmax, float* __restrict__ pmin)
{
    int t = blockIdx.x*256 + threadIdx.x;   // 4,194,304 total
    pmax[t] = -3e38f; pmin[t] = 3e38f;
}

__global__ void cvtW(const float* __restrict__ src, short* __restrict__ dst, int n)
{
    int t = blockIdx.x*256 + threadIdx.x;
    if (t < n) dst[t] = (short)f2bf(src[t]);
}

// ---------------- KNN (unchanged, verified) ----------------
__global__ __launch_bounds__(256)
void knn_kernel(const float* __restrict__ x, int* __restrict__ idx)
{
    #pragma clang fp contract(off)
    __shared__ float sx[3*NPTS];
    const int b  = blockIdx.x / (NPTS/4);
    const int nb = blockIdx.x % (NPTS/4);
    const float* xb = x + (size_t)b*3*NPTS;
    for (int i = threadIdx.x; i < 3*NPTS; i += 256) sx[i] = xb[i];
    __syncthreads();

    const int wave = threadIdx.x >> 6;
    const int lane = threadIdx.x & 63;
    const int n = nb*4 + wave;

    const float x0 = sx[n], x1 = sx[NPTS+n], x2 = sx[2*NPTS+n];
    const float xxn = x0*x0 + x1*x1 + x2*x2;

    float best[KNN]; int bi[KNN];
    #pragma unroll
    for (int i = 0; i < KNN; ++i) { best[i] = -3e38f; bi[i] = 0x7fffffff; }

    #pragma unroll
    for (int j = 0; j < NPTS/64; ++j) {
        int m = lane + j*64;
        float y0 = sx[m], y1 = sx[NPTS+m], y2 = sx[2*NPTS+m];
        float dot = x0*y0 + x1*y1 + x2*y2;
        float xxm = y0*y0 + y1*y1 + y2*y2;
        float v = -xxn - (-2.f*dot) - xxm;
        int mi = m;
        #pragma unroll
        for (int i = 0; i < KNN; ++i) {
            bool sw = v > best[i];
            float tv = sw ? best[i] : v;
            int   ti = sw ? bi[i]   : mi;
            best[i] = sw ? v  : best[i];
            bi[i]   = sw ? mi : bi[i];
            v = tv; mi = ti;
        }
    }
    size_t obase = ((size_t)b*NPTS + n)*KNN;
    #pragma unroll 1
    for (int s = 0; s < KNN; ++s) {
        float mv = best[0]; int mi = bi[0];
        #pragma unroll
        for (int off = 1; off < 64; off <<= 1) {
            float ov = __shfl_xor(mv, off);
            int   oi = __shfl_xor(mi, off);
            if (ov > mv || (ov == mv && oi < mi)) { mv = ov; mi = oi; }
        }
        bool win = (best[0] == mv) && (bi[0] == mi);
        #pragma unroll
        for (int i = 0; i < KNN-1; ++i) {
            best[i] = win ? best[i+1] : best[i];
            bi[i]   = win ? bi[i+1]   : bi[i];
        }
        best[KNN-1] = win ? -3e38f     : best[KNN-1];
        bi[KNN-1]   = win ? 0x7fffffff : bi[KNN-1];
        if (lane == 0) idx[obase + s] = mi;
    }
}

// ---------------- conv1: edge features + 6->64 conv, r-major output ----------------
__global__ void conv1T(const float* __restrict__ x, const int* __restrict__ idx,
                       const float* __restrict__ W1, bf16* __restrict__ h1)
{
    int p = blockIdx.x*256 + threadIdx.x;   // flat row br
    int b = p / NK;
    int r = p - b*NK;
    int n = r / KNN;
    int j = idx[p];
    const float* xb = x + (size_t)b*3*NPTS;
    float c0 = xb[n], c1 = xb[NPTS+n], c2 = xb[2*NPTS+n];
    float d0 = xb[j]-c0, d1 = xb[NPTS+j]-c1, d2 = xb[2*NPTS+j]-c2;
    uint4* outp = reinterpret_cast<uint4*>(reinterpret_cast<unsigned short*>(h1) + (size_t)p*64);
    #pragma unroll
    for (int ch = 0; ch < 8; ++ch) {
        uint u[4];
        #pragma unroll
        for (int q = 0; q < 4; ++q) {
            const float* wa = W1 + (ch*8 + q*2)*6;
            float a0 = wa[0]*d0 + wa[1]*d1 + wa[2]*d2 + wa[3]*c0 + wa[4]*c1 + wa[5]*c2;
            const float* wb = wa + 6;
            float a1 = wb[0]*d0 + wb[1]*d1 + wb[2]*d2 + wb[3]*c0 + wb[4]*c1 + wb[5]*c2;
            u[q] = (uint)f2bf(a0) | ((uint)f2bf(a1) << 16);
        }
        outp[ch] = make_uint4(u[0], u[1], u[2], u[3]);
    }
}

// ---------------- layer-1 stats on r-major h1 ----------------
__global__ void statsT64(const bf16* __restrict__ h, float* __restrict__ shadow)
{
    __shared__ float ls[4][64], lq[4][64];
    int t = threadIdx.x;
    int c = t & 63, grp = t >> 6;
    const unsigned short* hp = reinterpret_cast<const unsigned short*>(h);
    size_t base = (size_t)blockIdx.x*1024;
    float s = 0.f, q = 0.f;
    for (int it = 0; it < 256; ++it) {
        size_t br = base + grp + (size_t)it*4;
        float v = bfu2f(hp[br*64 + c]);
        s += v; q += v*v;
    }
    ls[grp][c] = s; lq[grp][c] = q;
    __syncthreads();
    if (t < 64) {
        float S = ls[0][t]+ls[1][t]+ls[2][t]+ls[3][t];
        float Q = lq[0][t]+lq[1][t]+lq[2][t]+lq[3][t];
        float* sh = shadow + (size_t)(blockIdx.x & 15)*1024;
        atomicAdd(&sh[t], S);
        atomicAdd(&sh[512 + t], Q);
    }
}

// ---------------- fold shadows -> mean/rstd -> (sc,bi) in bf16-pack + f32 ----------------
__global__ void fin_kernel(const float* __restrict__ shadow,
                           const float* __restrict__ gamma, const float* __restrict__ beta,
                           uint* __restrict__ scbiU, float* __restrict__ scbiF,
                           int C, float invCnt)
{
    for (int c = threadIdx.x; c < C; c += 256) {
        float s = 0.f, q = 0.f;
        #pragma unroll
        for (int i = 0; i < 16; ++i) { s += shadow[i*1024 + c]; q += shadow[i*1024 + 512 + c]; }
        float m = s*invCnt;
        float var = q*invCnt - m*m;
        float rs = rsqrtf(var + 1e-5f);
        float sc = rs * gamma[c];
        float bi = fmaf(-m, sc, beta[c]);
        scbiF[2*c] = sc; scbiF[2*c+1] = bi;
        scbiU[c] = ((uint)f2bf(bi) << 16) | (uint)f2bf(sc);
    }
}

// ---------------- MFMA GEMM, M row-tiles per wave ----------------
// out[br][co] = sum_ci W[co][ci] * relu(in[br][ci]*sc+bi); r-major in/out.
// Block = 4 waves x (M*16) rows = 64*M rows, Cout/NSPLIT cols (blockIdx.y).
// Fused per-channel stats; optional fused k-group max/min pooling (layer 4).
template<int Cout, int Cin, int M, int POOL, int NSPLIT>
__global__ __launch_bounds__(256)
void gemmT(const short* __restrict__ Wb, const bf16* __restrict__ in,
           const uint* __restrict__ scbi, bf16* __restrict__ outT,
           float* __restrict__ shadow, float* __restrict__ pmax, float* __restrict__ pmin)
{
    constexpr int NT = Cout/(16*NSPLIT);
    constexpr int KS = Cin/32;
    constexpr int ROWS = 64*M;
    constexpr int NGMAX = ROWS/KNN + 2;
    const int tid  = threadIdx.x;
    const int lane = tid & 63;
    const int g = lane >> 4, mr = lane & 15;
    const int wid = tid >> 6;
    const int rowBlk = blockIdx.x*ROWS;
    const int rowW   = rowBlk + wid*(16*M);
    const int ntBase = blockIdx.y*(NT*16);

    __shared__ uint pmx[POOL ? NGMAX*256 : 1];
    __shared__ uint pmn[POOL ? NGMAX*256 : 1];
    const int gblk0 = rowBlk/KNN;
    if (POOL) {
        for (int e = tid; e < NGMAX*256; e += 256){ pmx[e] = 0u; pmn[e] = 0xFFFFFFFFu; }
        __syncthreads();
    }

    f32x4 acc[M][NT];
    #pragma unroll
    for (int m = 0; m < M; ++m)
    #pragma unroll
    for (int i = 0; i < NT; ++i) acc[m][i] = (f32x4){0.f,0.f,0.f,0.f};

    const short* inS = reinterpret_cast<const short*>(in);
    for (int ks = 0; ks < KS; ++ks) {
        const int k0 = ks*32 + 8*g;
        const uint4* sp = reinterpret_cast<const uint4*>(scbi + k0);
        uint4 s0 = sp[0], s1 = sp[1];
        uint se[8] = {s0.x, s0.y, s0.z, s0.w, s1.x, s1.y, s1.z, s1.w};
        short8v a[M];
        #pragma unroll
        for (int m = 0; m < M; ++m) {
            short8v araw = *reinterpret_cast<const short8v*>(
                inS + (size_t)(rowW + m*16 + mr)*Cin + k0);
            #pragma unroll
            for (int e = 0; e < 8; ++e) {
                float v  = __uint_as_float(((uint)(unsigned short)araw[e]) << 16);
                float sc = __uint_as_float(se[e] << 16);
                float bi = __uint_as_float(se[e] & 0xffff0000u);
                a[m][e] = (short)f2bf(fmaxf(fmaf(v, sc, bi), 0.f));
            }
        }
        #pragma unroll
        for (int nt = 0; nt < NT; ++nt) {
            short8v bfr = *reinterpret_cast<const short8v*>(
                Wb + (size_t)(ntBase + nt*16 + mr)*Cin + k0);
            #pragma unroll
            for (int m = 0; m < M; ++m)
                acc[m][nt] = __builtin_amdgcn_mfma_f32_16x16x32_bf16(a[m], bfr, acc[m][nt], 0, 0, 0);
        }
    }

    if (!POOL) {
        #pragma unroll
        for (int m = 0; m < M; ++m)
        #pragma unroll
        for (int nt = 0; nt < NT; ++nt)
        #pragma unroll
        for (int j = 0; j < 4; ++j) {
            size_t row = (size_t)rowW + m*16 + g*4 + j;
            outT[row*Cout + ntBase + nt*16 + mr] = __float2bfloat16(acc[m][nt][j]);
        }
    } else {
        #pragma unroll
        for (int m = 0; m < M; ++m) {
            const int brow = rowW + m*16 + g*4;
            #pragma unroll
            for (int nt = 0; nt < NT; ++nt) {
                int c = ntBase + nt*16 + mr;
                int gcur = brow / KNN;
                float mx = acc[m][nt][0], mn = acc[m][nt][0];
                #pragma unroll
                for (int j = 1; j < 4; ++j) {
                    int gj = (brow + j) / KNN;
                    if (gj != gcur) {
                        atomicMax(&pmx[(gcur-gblk0)*256 + c], fenc(mx));
                        atomicMin(&pmn[(gcur-gblk0)*256 + c], fenc(mn));
                        gcur = gj; mx = acc[m][nt][j]; mn = acc[m][nt][j];
                    } else { mx = fmaxf(mx, acc[m][nt][j]); mn = fminf(mn, acc[m][nt][j]); }
                }
                atomicMax(&pmx[(gcur-gblk0)*256 + c], fenc(mx));
                atomicMin(&pmn[(gcur-gblk0)*256 + c], fenc(mn));
            }
        }
    }

    // fused per-channel stats (rows combined across m in-register first)
    float* sh = shadow + (size_t)((blockIdx.x ^ blockIdx.y) & 15)*1024;
    #pragma unroll
    for (int nt = 0; nt < NT; ++nt) {
        float s = 0.f, q = 0.f;
        #pragma unroll
        for (int m = 0; m < M; ++m)
        #pragma unroll
        for (int j = 0; j < 4; ++j) { float v = acc[m][nt][j]; s += v; q += v*v; }
        s += __shfl_xor(s, 16); s += __shfl_xor(s, 32);
        q += __shfl_xor(q, 16); q += __shfl_xor(q, 32);
        if (g == 0) {
            atomicAdd(&sh[ntBase + nt*16 + mr], s);
            atomicAdd(&sh[512 + ntBase + nt*16 + mr], q);
        }
    }

    if (POOL) {
        __syncthreads();
        const int ng = (rowBlk + ROWS - 1)/KNN - gblk0 + 1;
        const int b0 = rowBlk, b1 = rowBlk + ROWS - 1;
        for (int e = tid; e < ng*256; e += 256) {
            int gl = e >> 8, c = e & 255;
            int grp = gblk0 + gl;            // flat bn index
            int rfirst = grp*KNN, rlast = rfirst + KNN - 1;
            float vmx = fdec(pmx[e]), vmn = fdec(pmn[e]);
            float* pa = pmax + (size_t)grp*256 + c;
            float* pb = pmin + (size_t)grp*256 + c;
            if (rfirst >= b0 && rlast <= b1) { *pa = vmx; *pb = vmn; }
            else { atomicMaxF(pa, vmx); atomicMinF(pb, vmn); }
        }
    }
}

// ---------------- k-maxpool (bn+relu on the fly) into cat_T ----------------
template<int C>
__global__ void maxpoolT(const bf16* __restrict__ h, const float* __restrict__ scbiF,
                         bf16* __restrict__ catT, int coff)
{
    constexpr int PB = 256/C;
    int t = threadIdx.x;
    int c = t & (C-1);
    int bn = blockIdx.x*PB + t/C;
    float sc = scbiF[2*c], bi = scbiF[2*c+1];
    const unsigned short* src = reinterpret_cast<const unsigned short*>(h) + (size_t)bn*KNN*C + c;
    float best = -3e38f;
    #pragma unroll
    for (int kk = 0; kk < KNN; ++kk)
        best = fmaxf(best, fmaf(bfu2f(src[kk*C]), sc, bi));
    catT[(size_t)bn*512 + coff + c] = __float2bfloat16(fmaxf(best, 0.f));
}

// ---------------- layer-4 pooled raw -> BN+ReLU -> cat_T[256:512] ----------------
__global__ void cat4T(const float* __restrict__ pmax, const float* __restrict__ pmin,
                      const float* __restrict__ scbiF, const float* __restrict__ g4,
                      bf16* __restrict__ catT)
{
    int t = blockIdx.x*256 + threadIdx.x;   // bn*256 + c
    int c = t & 255, bn = t >> 8;
    float sc = scbiF[2*c], bi = scbiF[2*c+1];
    float v = (g4[c] >= 0.f) ? pmax[t] : pmin[t];
    catT[(size_t)bn*512 + 256 + c] = __float2bfloat16(fmaxf(fmaf(v, sc, bi), 0.f));
}

// ---------------- final BN+ReLU + transpose to [b][c][n] fp32 ----------------
__global__ void finalT(const bf16* __restrict__ h5, const float* __restrict__ scbiF,
                       float* __restrict__ out)
{
    __shared__ float ls[64][65];
    int t = threadIdx.x;
    int b = blockIdx.z, n0 = blockIdx.x*64, c0 = blockIdx.y*64;
    int j = t & 63, i0 = t >> 6;
    float sc = scbiF[2*(c0+j)], bi = scbiF[2*(c0+j)+1];
    const unsigned short* hp = reinterpret_cast<const unsigned short*>(h5);
    for (int it = 0; it < 16; ++it) {
        int i = i0 + it*4;
        float v = bfu2f(hp[((size_t)(b*NPTS + n0 + i))*512 + c0 + j]);
        ls[i][j] = fmaxf(fmaf(v, sc, bi), 0.f);
    }
    __syncthreads();
    for (int it = 0; it < 16; ++it) {
        int cr = i0 + it*4;
        out[((size_t)b*512 + c0 + cr)*NPTS + n0 + j] = ls[j][cr];
    }
}

extern "C" void kernel_launch(void* const* d_in, const int* in_sizes, int n_in,
                              void* d_out, int out_size, void* d_ws, size_t ws_size,
                              hipStream_t stream)
{
    const float* x  = (const float*)d_in[0];
    const float* W1 = (const float*)d_in[2];
    const float* W2 = (const float*)d_in[3];
    const float* W3 = (const float*)d_in[4];
    const float* W4 = (const float*)d_in[5];
    const float* W5 = (const float*)d_in[6];
    const float* g1 = (const float*)d_in[7];  const float* b1 = (const float*)d_in[8];
    const float* g2 = (const float*)d_in[9];  const float* b2 = (const float*)d_in[10];
    const float* g3 = (const float*)d_in[11]; const float* b3 = (const float*)d_in[12];
    const float* g4 = (const float*)d_in[13]; const float* b4 = (const float*)d_in[14];
    const float* g5 = (const float*)d_in[15]; const float* b5 = (const float*)d_in[16];
    float* out = (float*)d_out;

    // workspace layout (~178 MiB):
    char* w = (char*)d_ws;
    int*   idx    = (int*)w;                          // 1,310,720 B
    uint*  scbiU  = (uint*)(w + 1310720);             // [6][512] u32
    float* scbiF  = (float*)(w + 1323008);            // [5][512][2] f32
    float* shadow = (float*)(w + 1343488);            // [5][16][1024] f32
    short* Wb     = (short*)(w + 1671168);            // bf16 weights, 307200 elems
    bf16*  h1     = (bf16*)(w + 2285568);             // [P4][64]   42MB
    float* pmax   = (float*)h1;                       // alias h1 (dead) [16384][256]
    float* pmin   = pmax + (size_t)BN_TOT*256;
    bf16*  h2     = (bf16*)(w + 44228608);            // [P4][64]   42MB
    bf16*  h5     = h2;                               // alias h2 (dead) [16384][512]
    bf16*  h3     = (bf16*)(w + 86171648);            // [P4][128]  84MB
    bf16*  catT   = (bf16*)(w + 170057728);           // [16384][512] 16.8MB

    short* Wb2 = Wb, *Wb3 = Wb + 4096, *Wb4 = Wb + 12288, *Wb5 = Wb + 45056;
    float* sh1 = shadow, *sh2 = shadow + 16384, *sh3 = shadow + 2*16384,
         * sh4 = shadow + 3*16384, *sh5 = shadow + 4*16384;

    initK<<<320, 256, 0, stream>>>(shadow, scbiU + 5*512);
    cvtW<<<16,   256, 0, stream>>>(W2, Wb2, 4096);
    cvtW<<<32,   256, 0, stream>>>(W3, Wb3, 8192);
    cvtW<<<128,  256, 0, stream>>>(W4, Wb4, 32768);
    cvtW<<<1024, 256, 0, stream>>>(W5, Wb5, 262144);

    knn_kernel<<<BATCH*NPTS/4, 256, 0, stream>>>(x, idx);
    conv1T<<<P4/256, 256, 0, stream>>>(x, idx, W1, h1);

    statsT64<<<320, 256, 0, stream>>>(h1, sh1);
    fin_kernel<<<1, 256, 0, stream>>>(sh1, g1, b1, scbiU, scbiF, 64, 1.f/P4);
    maxpoolT<64><<<BN_TOT/4, 256, 0, stream>>>(h1, scbiF, catT, 0);

    // layer 2: 256 rows/block (M=4)
    gemmT<64,64,4,0,1><<<P4/256, 256, 0, stream>>>(Wb2, h1, scbiU, h2, sh2, nullptr, nullptr);
    fin_kernel<<<1, 256, 0, stream>>>(sh2, g2, b2, scbiU + 512, scbiF + 1024, 64, 1.f/P4);
    maxpoolT<64><<<BN_TOT/4, 256, 0, stream>>>(h2, scbiF + 1024, catT, 64);

    // layer 3
    gemmT<128,64,4,0,1><<<P4/256, 256, 0, stream>>>(Wb3, h2, scbiU + 512, h3, sh3, nullptr, nullptr);
    fin_kernel<<<1, 256, 0, stream>>>(sh3, g3, b3, scbiU + 1024, scbiF + 2048, 128, 1.f/P4);
    maxpoolT<128><<<BN_TOT/2, 256, 0, stream>>>(h3, scbiF + 2048, catT, 128);

    // layer 4: fused pool, 128 rows/block (M=2)
    poolInit<<<BN_TOT*256/256, 256, 0, stream>>>(pmax, pmin);   // h1 dead now
    gemmT<256,128,2,1,1><<<P4/128, 256, 0, stream>>>(Wb4, h3, scbiU + 1024, nullptr, sh4, pmax, pmin);
    fin_kernel<<<1, 256, 0, stream>>>(sh4, g4, b4, scbiU + 1536, scbiF + 3072, 256, 1.f/P4);
    cat4T<<<BN_TOT, 256, 0, stream>>>(pmax, pmin, scbiF + 3072, g4, catT);

    // layer 5: Cout split 4-way, 256 rows/block
    gemmT<512,512,4,0,4><<<dim3(BN_TOT/256, 4), 256, 0, stream>>>(Wb5, catT, scbiU + 5*512, h5, sh5, nullptr, nullptr);
    fin_kernel<<<1, 256, 0, stream>>>(sh5, g5, b5, scbiU + 2048, scbiF + 4096, 512, 1.f/BN_TOT);
    finalT<<<dim3(NPTS/64, 8, BATCH), 256, 0, stream>>>(h5, scbiF + 4096, out);
}

// Round 7
// 527.927 us; speedup vs baseline: 12.1342x; 1.0160x over previous
//
#include <hip/hip_runtime.h>
#include <hip/hip_bf16.h>

typedef __hip_bfloat16 bf16;
typedef __attribute__((ext_vector_type(8))) short short8v;
typedef __attribute__((ext_vector_type(4))) float f32x4;
typedef unsigned int uint;

#define BATCH 8
#define NPTS 2048
#define KNN 20
#define NK (NPTS*KNN)      // 40960
#define P4 (BATCH*NK)      // 327680
#define BN_TOT (BATCH*NPTS) // 16384

union BU { bf16 h; unsigned short u; };
__device__ __forceinline__ unsigned short f2bf(float f){
    BU bu; bu.h = __float2bfloat16(f); return bu.u;
}
__device__ __forceinline__ float bfu2f(unsigned short u){
    return __uint_as_float(((uint)u) << 16);
}

// float atomic max/min via integer punning (init -inf/+inf)
__device__ __forceinline__ void atomicMaxF(float* a, float v){
    if (v >= 0.f) atomicMax((int*)a, __float_as_int(v));
    else          atomicMin((unsigned int*)a, (unsigned int)__float_as_int(v));
}
__device__ __forceinline__ void atomicMinF(float* a, float v){
    if (v >= 0.f) atomicMin((int*)a, __float_as_int(v));
    else          atomicMax((unsigned int*)a, (unsigned int)__float_as_int(v));
}
// monotone flip encoding: unsigned compare == float compare
__device__ __forceinline__ uint fenc(float f){
    uint b = __float_as_uint(f);
    return (b & 0x80000000u) ? ~b : (b | 0x80000000u);
}
__device__ __forceinline__ float fdec(uint u){
    uint b = (u & 0x80000000u) ? (u & 0x7fffffffu) : ~u;
    return __uint_as_float(b);
}

// ---------------- init: zero shadow stats, identity scbi for layer-5 input ----------------
__global__ void initK(float* __restrict__ shadow, uint* __restrict__ scbiU5)
{
    int t = blockIdx.x*256 + threadIdx.x;
    if (t < 5*16*1024) shadow[t] = 0.f;
    if (t < 512) scbiU5[t] = 0x00003F80u;   // sc=1.0bf16, bi=0
}

__global__ void poolInit(float* __restrict__ pmax, float* __restrict__ pmin)
{
    int t = blockIdx.x*256 + threadIdx.x;   // 4,194,304 total
    pmax[t] = -3e38f; pmin[t] = 3e38f;
}

__global__ void cvtW(const float* __restrict__ src, short* __restrict__ dst, int n)
{
    int t = blockIdx.x*256 + threadIdx.x;
    if (t < n) dst[t] = (short)f2bf(src[t]);
}

// ---------------- KNN (unchanged, verified) ----------------
__global__ __launch_bounds__(256)
void knn_kernel(const float* __restrict__ x, int* __restrict__ idx)
{
    #pragma clang fp contract(off)
    __shared__ float sx[3*NPTS];
    const int b  = blockIdx.x / (NPTS/4);
    const int nb = blockIdx.x % (NPTS/4);
    const float* xb = x + (size_t)b*3*NPTS;
    for (int i = threadIdx.x; i < 3*NPTS; i += 256) sx[i] = xb[i];
    __syncthreads();

    const int wave = threadIdx.x >> 6;
    const int lane = threadIdx.x & 63;
    const int n = nb*4 + wave;

    const float x0 = sx[n], x1 = sx[NPTS+n], x2 = sx[2*NPTS+n];
    const float xxn = x0*x0 + x1*x1 + x2*x2;

    float best[KNN]; int bi[KNN];
    #pragma unroll
    for (int i = 0; i < KNN; ++i) { best[i] = -3e38f; bi[i] = 0x7fffffff; }

    #pragma unroll
    for (int j = 0; j < NPTS/64; ++j) {
        int m = lane + j*64;
        float y0 = sx[m], y1 = sx[NPTS+m], y2 = sx[2*NPTS+m];
        float dot = x0*y0 + x1*y1 + x2*y2;
        float xxm = y0*y0 + y1*y1 + y2*y2;
        float v = -xxn - (-2.f*dot) - xxm;
        int mi = m;
        #pragma unroll
        for (int i = 0; i < KNN; ++i) {
            bool sw = v > best[i];
            float tv = sw ? best[i] : v;
            int   ti = sw ? bi[i]   : mi;
            best[i] = sw ? v  : best[i];
            bi[i]   = sw ? mi : bi[i];
            v = tv; mi = ti;
        }
    }
    size_t obase = ((size_t)b*NPTS + n)*KNN;
    #pragma unroll 1
    for (int s = 0; s < KNN; ++s) {
        float mv = best[0]; int mi = bi[0];
        #pragma unroll
        for (int off = 1; off < 64; off <<= 1) {
            float ov = __shfl_xor(mv, off);
            int   oi = __shfl_xor(mi, off);
            if (ov > mv || (ov == mv && oi < mi)) { mv = ov; mi = oi; }
        }
        bool win = (best[0] == mv) && (bi[0] == mi);
        #pragma unroll
        for (int i = 0; i < KNN-1; ++i) {
            best[i] = win ? best[i+1] : best[i];
            bi[i]   = win ? bi[i+1]   : bi[i];
        }
        best[KNN-1] = win ? -3e38f     : best[KNN-1];
        bi[KNN-1]   = win ? 0x7fffffff : bi[KNN-1];
        if (lane == 0) idx[obase + s] = mi;
    }
}

// ---------------- conv1: edge features + 6->64 conv, r-major output ----------------
__global__ void conv1T(const float* __restrict__ x, const int* __restrict__ idx,
                       const float* __restrict__ W1, bf16* __restrict__ h1)
{
    int p = blockIdx.x*256 + threadIdx.x;   // flat row br
    int b = p / NK;
    int r = p - b*NK;
    int n = r / KNN;
    int j = idx[p];
    const float* xb = x + (size_t)b*3*NPTS;
    float c0 = xb[n], c1 = xb[NPTS+n], c2 = xb[2*NPTS+n];
    float d0 = xb[j]-c0, d1 = xb[NPTS+j]-c1, d2 = xb[2*NPTS+j]-c2;
    uint4* outp = reinterpret_cast<uint4*>(reinterpret_cast<unsigned short*>(h1) + (size_t)p*64);
    #pragma unroll
    for (int ch = 0; ch < 8; ++ch) {
        uint u[4];
        #pragma unroll
        for (int q = 0; q < 4; ++q) {
            const float* wa = W1 + (ch*8 + q*2)*6;
            float a0 = wa[0]*d0 + wa[1]*d1 + wa[2]*d2 + wa[3]*c0 + wa[4]*c1 + wa[5]*c2;
            const float* wb = wa + 6;
            float a1 = wb[0]*d0 + wb[1]*d1 + wb[2]*d2 + wb[3]*c0 + wb[4]*c1 + wb[5]*c2;
            u[q] = (uint)f2bf(a0) | ((uint)f2bf(a1) << 16);
        }
        outp[ch] = make_uint4(u[0], u[1], u[2], u[3]);
    }
}

// ---------------- layer-1 stats on r-major h1 ----------------
__global__ void statsT64(const bf16* __restrict__ h, float* __restrict__ shadow)
{
    __shared__ float ls[4][64], lq[4][64];
    int t = threadIdx.x;
    int c = t & 63, grp = t >> 6;
    const unsigned short* hp = reinterpret_cast<const unsigned short*>(h);
    size_t base = (size_t)blockIdx.x*1024;
    float s = 0.f, q = 0.f;
    for (int it = 0; it < 256; ++it) {
        size_t br = base + grp + (size_t)it*4;
        float v = bfu2f(hp[br*64 + c]);
        s += v; q += v*v;
    }
    ls[grp][c] = s; lq[grp][c] = q;
    __syncthreads();
    if (t < 64) {
        float S = ls[0][t]+ls[1][t]+ls[2][t]+ls[3][t];
        float Q = lq[0][t]+lq[1][t]+lq[2][t]+lq[3][t];
        float* sh = shadow + (size_t)(blockIdx.x & 15)*1024;
        atomicAdd(&sh[t], S);
        atomicAdd(&sh[512 + t], Q);
    }
}

// ---------------- fold shadows -> mean/rstd -> (sc,bi) in bf16-pack + f32 ----------------
__global__ void fin_kernel(const float* __restrict__ shadow,
                           const float* __restrict__ gamma, const float* __restrict__ beta,
                           uint* __restrict__ scbiU, float* __restrict__ scbiF,
                           int C, float invCnt)
{
    for (int c = threadIdx.x; c < C; c += 256) {
        float s = 0.f, q = 0.f;
        #pragma unroll
        for (int i = 0; i < 16; ++i) { s += shadow[i*1024 + c]; q += shadow[i*1024 + 512 + c]; }
        float m = s*invCnt;
        float var = q*invCnt - m*m;
        float rs = rsqrtf(var + 1e-5f);
        float sc = rs * gamma[c];
        float bi = fmaf(-m, sc, beta[c]);
        scbiF[2*c] = sc; scbiF[2*c+1] = bi;
        scbiU[c] = ((uint)f2bf(bi) << 16) | (uint)f2bf(sc);
    }
}

// ---------------- MFMA GEMM, pipelined A loads, Cout split across blockIdx.y ----------------
// out[br][co] = sum_ci W[co][ci] * relu(in[br][ci]*sc+bi); r-major in/out.
// Block = 4 waves x (M*16) rows; cols [blockIdx.y*CSPL, +CSPL).
// Fused per-channel stats; optional fused k-group max/min pooling (layer 4).
template<int Cout, int Cin, int M, int POOL, int NSPLIT>
__global__ __launch_bounds__(256)
void gemmT(const short* __restrict__ Wb, const bf16* __restrict__ in,
           const uint* __restrict__ scbi, bf16* __restrict__ outT,
           float* __restrict__ shadow, float* __restrict__ pmax, float* __restrict__ pmin)
{
    constexpr int CSPL = Cout/NSPLIT;
    constexpr int NT = CSPL/16;
    constexpr int KS = Cin/32;
    constexpr int ROWS = 64*M;
    constexpr int NGMAX = ROWS/KNN + 2;
    const int tid  = threadIdx.x;
    const int lane = tid & 63;
    const int g = lane >> 4, mr = lane & 15;
    const int wid = tid >> 6;
    const int rowBlk = blockIdx.x*ROWS;
    const int rowW   = rowBlk + wid*(16*M);
    const int ntBase = blockIdx.y*CSPL;

    __shared__ uint pmx[POOL ? NGMAX*CSPL : 1];
    __shared__ uint pmn[POOL ? NGMAX*CSPL : 1];
    const int gblk0 = rowBlk/KNN;
    if (POOL) {
        for (int e = tid; e < NGMAX*CSPL; e += 256){ pmx[e] = 0u; pmn[e] = 0xFFFFFFFFu; }
        __syncthreads();
    }

    f32x4 acc[M][NT];
    #pragma unroll
    for (int m = 0; m < M; ++m)
    #pragma unroll
    for (int i = 0; i < NT; ++i) acc[m][i] = (f32x4){0.f,0.f,0.f,0.f};

    const short* inS = reinterpret_cast<const short*>(in);

    // prologue: load A fragments for ks=0
    short8v araw[M], anext[M];
    #pragma unroll
    for (int m = 0; m < M; ++m)
        araw[m] = *reinterpret_cast<const short8v*>(inS + (size_t)(rowW + m*16 + mr)*Cin + 8*g);

    #pragma unroll
    for (int ks = 0; ks < KS; ++ks) {
        const int k0 = ks*32 + 8*g;
        // prefetch next A while computing current
        if (ks + 1 < KS) {
            const int k1 = (ks+1)*32 + 8*g;
            #pragma unroll
            for (int m = 0; m < M; ++m)
                anext[m] = *reinterpret_cast<const short8v*>(inS + (size_t)(rowW + m*16 + mr)*Cin + k1);
        }
        const uint4* sp = reinterpret_cast<const uint4*>(scbi + k0);
        uint4 s0 = sp[0], s1 = sp[1];
        uint se[8] = {s0.x, s0.y, s0.z, s0.w, s1.x, s1.y, s1.z, s1.w};
        short8v a[M];
        #pragma unroll
        for (int m = 0; m < M; ++m) {
            #pragma unroll
            for (int e = 0; e < 8; ++e) {
                float v  = __uint_as_float(((uint)(unsigned short)araw[m][e]) << 16);
                float sc = __uint_as_float(se[e] << 16);
                float bi = __uint_as_float(se[e] & 0xffff0000u);
                a[m][e] = (short)f2bf(fmaxf(fmaf(v, sc, bi), 0.f));
            }
        }
        #pragma unroll
        for (int nt = 0; nt < NT; ++nt) {
            short8v bfr = *reinterpret_cast<const short8v*>(
                Wb + (size_t)(ntBase + nt*16 + mr)*Cin + k0);
            #pragma unroll
            for (int m = 0; m < M; ++m)
                acc[m][nt] = __builtin_amdgcn_mfma_f32_16x16x32_bf16(a[m], bfr, acc[m][nt], 0, 0, 0);
        }
        #pragma unroll
        for (int m = 0; m < M; ++m) araw[m] = anext[m];
    }

    if (!POOL) {
        #pragma unroll
        for (int m = 0; m < M; ++m)
        #pragma unroll
        for (int nt = 0; nt < NT; ++nt)
        #pragma unroll
        for (int j = 0; j < 4; ++j) {
            size_t row = (size_t)rowW + m*16 + g*4 + j;
            outT[row*Cout + ntBase + nt*16 + mr] = __float2bfloat16(acc[m][nt][j]);
        }
    } else {
        #pragma unroll
        for (int m = 0; m < M; ++m) {
            const int brow = rowW + m*16 + g*4;
            #pragma unroll
            for (int nt = 0; nt < NT; ++nt) {
                int cl = nt*16 + mr;
                int gcur = brow / KNN;
                float mx = acc[m][nt][0], mn = acc[m][nt][0];
                #pragma unroll
                for (int j = 1; j < 4; ++j) {
                    int gj = (brow + j) / KNN;
                    if (gj != gcur) {
                        atomicMax(&pmx[(gcur-gblk0)*CSPL + cl], fenc(mx));
                        atomicMin(&pmn[(gcur-gblk0)*CSPL + cl], fenc(mn));
                        gcur = gj; mx = acc[m][nt][j]; mn = acc[m][nt][j];
                    } else { mx = fmaxf(mx, acc[m][nt][j]); mn = fminf(mn, acc[m][nt][j]); }
                }
                atomicMax(&pmx[(gcur-gblk0)*CSPL + cl], fenc(mx));
                atomicMin(&pmn[(gcur-gblk0)*CSPL + cl], fenc(mn));
            }
        }
    }

    // fused per-channel stats (rows combined across m in-register first)
    float* sh = shadow + (size_t)((blockIdx.x ^ blockIdx.y) & 15)*1024;
    #pragma unroll
    for (int nt = 0; nt < NT; ++nt) {
        float s = 0.f, q = 0.f;
        #pragma unroll
        for (int m = 0; m < M; ++m)
        #pragma unroll
        for (int j = 0; j < 4; ++j) { float v = acc[m][nt][j]; s += v; q += v*v; }
        s += __shfl_xor(s, 16); s += __shfl_xor(s, 32);
        q += __shfl_xor(q, 16); q += __shfl_xor(q, 32);
        if (g == 0) {
            atomicAdd(&sh[ntBase + nt*16 + mr], s);
            atomicAdd(&sh[512 + ntBase + nt*16 + mr], q);
        }
    }

    if (POOL) {
        __syncthreads();
        const int ng = (rowBlk + ROWS - 1)/KNN - gblk0 + 1;
        const int b0 = rowBlk, b1 = rowBlk + ROWS - 1;
        for (int e = tid; e < ng*CSPL; e += 256) {
            int gl = e / CSPL, cl = e % CSPL;
            int grp = gblk0 + gl;            // flat bn index
            int c = ntBase + cl;
            int rfirst = grp*KNN, rlast = rfirst + KNN - 1;
            float vmx = fdec(pmx[e]), vmn = fdec(pmn[e]);
            float* pa = pmax + (size_t)grp*256 + c;
            float* pb = pmin + (size_t)grp*256 + c;
            if (rfirst >= b0 && rlast <= b1) { *pa = vmx; *pb = vmn; }
            else { atomicMaxF(pa, vmx); atomicMinF(pb, vmn); }
        }
    }
}

// ---------------- k-maxpool (bn+relu on the fly) into cat_T ----------------
template<int C>
__global__ void maxpoolT(const bf16* __restrict__ h, const float* __restrict__ scbiF,
                         bf16* __restrict__ catT, int coff)
{
    constexpr int PB = 256/C;
    int t = threadIdx.x;
    int c = t & (C-1);
    int bn = blockIdx.x*PB + t/C;
    float sc = scbiF[2*c], bi = scbiF[2*c+1];
    const unsigned short* src = reinterpret_cast<const unsigned short*>(h) + (size_t)bn*KNN*C + c;
    float best = -3e38f;
    #pragma unroll
    for (int kk = 0; kk < KNN; ++kk)
        best = fmaxf(best, fmaf(bfu2f(src[kk*C]), sc, bi));
    catT[(size_t)bn*512 + coff + c] = __float2bfloat16(fmaxf(best, 0.f));
}

// ---------------- layer-4 pooled raw -> BN+ReLU -> cat_T[256:512] ----------------
__global__ void cat4T(const float* __restrict__ pmax, const float* __restrict__ pmin,
                      const float* __restrict__ scbiF, const float* __restrict__ g4,
                      bf16* __restrict__ catT)
{
    int t = blockIdx.x*256 + threadIdx.x;   // bn*256 + c
    int c = t & 255, bn = t >> 8;
    float sc = scbiF[2*c], bi = scbiF[2*c+1];
    float v = (g4[c] >= 0.f) ? pmax[t] : pmin[t];
    catT[(size_t)bn*512 + 256 + c] = __float2bfloat16(fmaxf(fmaf(v, sc, bi), 0.f));
}

// ---------------- final BN+ReLU + transpose to [b][c][n] fp32 ----------------
__global__ void finalT(const bf16* __restrict__ h5, const float* __restrict__ scbiF,
                       float* __restrict__ out)
{
    __shared__ float ls[64][65];
    int t = threadIdx.x;
    int b = blockIdx.z, n0 = blockIdx.x*64, c0 = blockIdx.y*64;
    int j = t & 63, i0 = t >> 6;
    float sc = scbiF[2*(c0+j)], bi = scbiF[2*(c0+j)+1];
    const unsigned short* hp = reinterpret_cast<const unsigned short*>(h5);
    for (int it = 0; it < 16; ++it) {
        int i = i0 + it*4;
        float v = bfu2f(hp[((size_t)(b*NPTS + n0 + i))*512 + c0 + j]);
        ls[i][j] = fmaxf(fmaf(v, sc, bi), 0.f);
    }
    __syncthreads();
    for (int it = 0; it < 16; ++it) {
        int cr = i0 + it*4;
        out[((size_t)b*512 + c0 + cr)*NPTS + n0 + j] = ls[j][cr];
    }
}

extern "C" void kernel_launch(void* const* d_in, const int* in_sizes, int n_in,
                              void* d_out, int out_size, void* d_ws, size_t ws_size,
                              hipStream_t stream)
{
    const float* x  = (const float*)d_in[0];
    const float* W1 = (const float*)d_in[2];
    const float* W2 = (const float*)d_in[3];
    const float* W3 = (const float*)d_in[4];
    const float* W4 = (const float*)d_in[5];
    const float* W5 = (const float*)d_in[6];
    const float* g1 = (const float*)d_in[7];  const float* b1 = (const float*)d_in[8];
    const float* g2 = (const float*)d_in[9];  const float* b2 = (const float*)d_in[10];
    const float* g3 = (const float*)d_in[11]; const float* b3 = (const float*)d_in[12];
    const float* g4 = (const float*)d_in[13]; const float* b4 = (const float*)d_in[14];
    const float* g5 = (const float*)d_in[15]; const float* b5 = (const float*)d_in[16];
    float* out = (float*)d_out;

    // workspace layout (~178 MiB):
    char* w = (char*)d_ws;
    int*   idx    = (int*)w;                          // 1,310,720 B
    uint*  scbiU  = (uint*)(w + 1310720);             // [6][512] u32
    float* scbiF  = (float*)(w + 1323008);            // [5][512][2] f32
    float* shadow = (float*)(w + 1343488);            // [5][16][1024] f32
    short* Wb     = (short*)(w + 1671168);             // bf16 weights, 307200 elems
    bf16*  h1     = (bf16*)(w + 2285568);             // [P4][64]   42MB
    float* pmax   = (float*)h1;                       // alias h1 (dead) [16384][256]
    float* pmin   = pmax + (size_t)BN_TOT*256;
    bf16*  h2     = (bf16*)(w + 44228608);            // [P4][64]   42MB
    bf16*  h5     = h2;                               // alias h2 (dead) [16384][512]
    bf16*  h3     = (bf16*)(w + 86171648);            // [P4][128]  84MB
    bf16*  catT   = (bf16*)(w + 170057728);           // [16384][512] 16.8MB

    short* Wb2 = Wb, *Wb3 = Wb + 4096, *Wb4 = Wb + 12288, *Wb5 = Wb + 45056;
    float* sh1 = shadow, *sh2 = shadow + 16384, *sh3 = shadow + 2*16384,
         * sh4 = shadow + 3*16384, *sh5 = shadow + 4*16384;

    initK<<<320, 256, 0, stream>>>(shadow, scbiU + 5*512);
    cvtW<<<16,   256, 0, stream>>>(W2, Wb2, 4096);
    cvtW<<<32,   256, 0, stream>>>(W3, Wb3, 8192);
    cvtW<<<128,  256, 0, stream>>>(W4, Wb4, 32768);
    cvtW<<<1024, 256, 0, stream>>>(W5, Wb5, 262144);

    knn_kernel<<<BATCH*NPTS/4, 256, 0, stream>>>(x, idx);
    conv1T<<<P4/256, 256, 0, stream>>>(x, idx, W1, h1);

    statsT64<<<320, 256, 0, stream>>>(h1, sh1);
    fin_kernel<<<1, 256, 0, stream>>>(sh1, g1, b1, scbiU, scbiF, 64, 1.f/P4);
    maxpoolT<64><<<BN_TOT/4, 256, 0, stream>>>(h1, scbiF, catT, 0);

    // layer 2: M=2, 128 rows/block
    gemmT<64,64,2,0,1><<<P4/128, 256, 0, stream>>>(Wb2, h1, scbiU, h2, sh2, nullptr, nullptr);
    fin_kernel<<<1, 256, 0, stream>>>(sh2, g2, b2, scbiU + 512, scbiF + 1024, 64, 1.f/P4);
    maxpoolT<64><<<BN_TOT/4, 256, 0, stream>>>(h2, scbiF + 1024, catT, 64);

    // layer 3: M=2
    gemmT<128,64,2,0,1><<<P4/128, 256, 0, stream>>>(Wb3, h2, scbiU + 512, h3, sh3, nullptr, nullptr);
    fin_kernel<<<1, 256, 0, stream>>>(sh3, g3, b3, scbiU + 1024, scbiF + 2048, 128, 1.f/P4);
    maxpoolT<128><<<BN_TOT/2, 256, 0, stream>>>(h3, scbiF + 2048, catT, 128);

    // layer 4: fused pool, M=2, Cout split 2-way
    poolInit<<<BN_TOT*256/256, 256, 0, stream>>>(pmax, pmin);   // h1 dead now
    gemmT<256,128,2,1,2><<<dim3(P4/128, 2), 256, 0, stream>>>(Wb4, h3, scbiU + 1024, nullptr, sh4, pmax, pmin);
    fin_kernel<<<1, 256, 0, stream>>>(sh4, g4, b4, scbiU + 1536, scbiF + 3072, 256, 1.f/P4);
    cat4T<<<BN_TOT, 256, 0, stream>>>(pmax, pmin, scbiF + 3072, g4, catT);

    // layer 5: Cout split 4-way, M=2
    gemmT<512,512,2,0,4><<<dim3(BN_TOT/128, 4), 256, 0, stream>>>(Wb5, catT, scbiU + 5*512, h5, sh5, nullptr, nullptr);
    fin_kernel<<<1, 256, 0, stream>>>(sh5, g5, b5, scbiU + 2048, scbiF + 4096, 512, 1.f/BN_TOT);
    finalT<<<dim3(NPTS/64, 8, BATCH), 256, 0, stream>>>(h5, scbiF + 4096, out);
}